// Round 4
// baseline (424.367 us; speedup 1.0000x reference)
//
#include <hip/hip_runtime.h>
#include <hip/hip_bf16.h>
#include <cstddef>

#define EE 1024            // E
#define MTOT 8192          // B*E

using floatx4 = __attribute__((ext_vector_type(4))) float;
using bf16x8  = __attribute__((ext_vector_type(8))) __bf16;

union FragU { uint4 u; bf16x8 b; };

__device__ __forceinline__ float elu1(float x) {
    return x > 0.f ? x + 1.f : __expf(x);
}

__device__ __forceinline__ unsigned int pack2bf(float x, float y) {
    __hip_bfloat162 h = __float22bfloat162_rn(make_float2(x, y));
    union { __hip_bfloat162 h; unsigned int u; } c;
    c.h = h;
    return c.u;
}

__device__ __forceinline__ uint4 pack8bf(const float4 a, const float4 b) {
    uint4 r;
    r.x = pack2bf(a.x, a.y); r.y = pack2bf(a.z, a.w);
    r.z = pack2bf(b.x, b.y); r.w = pack2bf(b.z, b.w);
    return r;
}

__device__ __forceinline__ unsigned short f2bf(float x) {
    union { __hip_bfloat16 h; unsigned short s; } c;
    c.h = __float2bfloat16(x);
    return c.s;
}

__device__ __forceinline__ void unp8(const uint4 p, float4& a, float4& b) {
    a.x = __uint_as_float(p.x << 16); a.y = __uint_as_float(p.x & 0xffff0000u);
    a.z = __uint_as_float(p.y << 16); a.w = __uint_as_float(p.y & 0xffff0000u);
    b.x = __uint_as_float(p.z << 16); b.y = __uint_as_float(p.z & 0xffff0000u);
    b.z = __uint_as_float(p.w << 16); b.w = __uint_as_float(p.w & 0xffff0000u);
}

// fp32 -> bf16 bulk convert, 8 elems/thread
__global__ __launch_bounds__(256)
void cvt_bf16(const float* __restrict__ src, unsigned short* __restrict__ dst, int n8) {
    const int i = blockIdx.x * 256 + threadIdx.x;
    if (i >= n8) return;
    const float4 a = ((const float4*)src)[2 * i];
    const float4 b = ((const float4*)src)[2 * i + 1];
    ((uint4*)dst)[i] = pack8bf(a, b);
}

// All four weight matrices in one launch.
__global__ __launch_bounds__(256)
void cvt_w(const float* __restrict__ Wq, const float* __restrict__ Wk,
           const float* __restrict__ Wv, const float* __restrict__ Wo,
           unsigned short* __restrict__ wb, unsigned short* __restrict__ wob) {
    const int i = blockIdx.x * 256 + threadIdx.x;
    if (i >= 917504) return;
    const float* src;
    unsigned short* dst;
    int off;
    if (i < 262144)      { src = Wq; dst = wb;           off = i; }
    else if (i < 524288) { src = Wk; dst = wb + 2097152; off = i - 262144; }
    else if (i < 786432) { src = Wv; dst = wb + 4194304; off = i - 524288; }
    else                 { src = Wo; dst = wob;          off = i - 786432; }
    const float4 a = ((const float4*)src)[2 * off];
    const float4 b = ((const float4*)src)[2 * off + 1];
    ((uint4*)dst)[off] = pack8bf(a, b);
}

// ============================================================================
// 256x256 reg-staged GEMM core. A[M][K] bf16, B[N][K]^T bf16 (row-major B^T).
// 8 waves (2m x 4n), per-wave 128x64 output (ratio 0.375 ds_read/MFMA),
// BK=64, double-buffered 128 KiB LDS.
//
// LDS: per tile, 16 row-groups of 16 rows; per (group, k-half) a 64-slot
// space of 16B chunks. Slot for (row r, chunk c):
//   slot(r,c) = (r&3) | (((r>>2)^c)&1)<<2 | (r&8) | ((c&3)<<4)
// Conflict-free BOTH sides (bank-group = slot&7):
//   read quarter-wave (c=quad fixed, r=lm=0..15): groups (r&3, r2^c0) -> each
//     of 8 groups exactly 2x  (round-2 measured: this 2x pattern = 0 conflicts)
//   write quarter-wave (r=4q..4q+3, c=0..3): groups (j, q0^c0) -> each 2x.
// (Round-3's linear write layout was 4-way conflicted: 2.92e7 cycles. This
// slot XOR is the fix; bijective, so reads fetch exactly what was written.)
//
// Staging: depth-1 reg pipeline (T14 split). Phase L: ds_read A(16)+Blow(4),
// issue 8 coalesced global_load_dwordx4 for K-step s+1; barrier; lgkm0;
// 32 MFMA. Phase H: ds_read Bhigh(4); [auto vmcnt] 8 ds_write_b128 into the
// other buffer; barrier; lgkm0; 32 MFMA. All loads register-tracked (exact
// waits, no stray DMA at endpgm).
// ============================================================================

#define BARD()  __builtin_amdgcn_s_barrier()
#define LGKM0() asm volatile("s_waitcnt lgkmcnt(0)" ::: "memory")
#define SB0()   __builtin_amdgcn_sched_barrier(0)
#define MF(va, vb, c) __builtin_amdgcn_mfma_f32_16x16x32_bf16((va).b, (vb).b, c, 0, 0, 0)

#define G_LOAD(KS) do {                                                      \
    const size_t ko_ = (size_t)(KS) * 64;                                    \
    Ra0 = *(const uint4*)(AsrcLo + ko_); Ra1 = *(const uint4*)(AsrcLo + ko_ + 32); \
    Ra2 = *(const uint4*)(AsrcHi + ko_); Ra3 = *(const uint4*)(AsrcHi + ko_ + 32); \
    Rb0 = *(const uint4*)(BsrcLo + ko_); Rb1 = *(const uint4*)(BsrcLo + ko_ + 32); \
    Rb2 = *(const uint4*)(BsrcHi + ko_); Rb3 = *(const uint4*)(BsrcHi + ko_ + 32); \
} while (0)

#define G_WRITE(SAp, SBp) do {                                               \
    *(uint4*)&SAp[gLo + wo]       = Ra0; *(uint4*)&SAp[gLo + 512 + wo] = Ra1; \
    *(uint4*)&SAp[gHi + wo]       = Ra2; *(uint4*)&SAp[gHi + 512 + wo] = Ra3; \
    *(uint4*)&SBp[gLo + wo]       = Rb0; *(uint4*)&SBp[gLo + 512 + wo] = Rb1; \
    *(uint4*)&SBp[gHi + wo]       = Rb2; *(uint4*)&SBp[gHi + 512 + wo] = Rb3; \
} while (0)

#define STEP(SAc, SBc, SAn, SBn, S) do {                                     \
    _Pragma("unroll")                                                        \
    for (int i2 = 0; i2 < 8; ++i2) {                                         \
        A8[i2][0].u = *(const uint4*)&SAc[(wr8 + i2) * 1024 + ro];           \
        A8[i2][1].u = *(const uint4*)&SAc[(wr8 + i2) * 1024 + 512 + ro];     \
    }                                                                        \
    _Pragma("unroll")                                                        \
    for (int j2 = 0; j2 < 2; ++j2) {                                         \
        Bq[j2][0].u = *(const uint4*)&SBc[(wc4 + j2) * 1024 + ro];           \
        Bq[j2][1].u = *(const uint4*)&SBc[(wc4 + j2) * 1024 + 512 + ro];     \
    }                                                                        \
    { const int kn_ = ((S) + 1 < NS) ? (S) + 1 : NS - 1; G_LOAD(kn_); }      \
    BARD(); LGKM0(); SB0();                                                  \
    __builtin_amdgcn_s_setprio(1);                                           \
    _Pragma("unroll")                                                        \
    for (int i2 = 0; i2 < 8; ++i2)                                           \
        _Pragma("unroll")                                                    \
        for (int j2 = 0; j2 < 2; ++j2) {                                     \
            acc[i2][j2] = MF(A8[i2][0], Bq[j2][0], acc[i2][j2]);             \
            acc[i2][j2] = MF(A8[i2][1], Bq[j2][1], acc[i2][j2]);             \
        }                                                                    \
    __builtin_amdgcn_s_setprio(0);                                           \
    BARD();                                                                  \
    _Pragma("unroll")                                                        \
    for (int j2 = 0; j2 < 2; ++j2) {                                         \
        Bq[j2][0].u = *(const uint4*)&SBc[(wc4 + 2 + j2) * 1024 + ro];       \
        Bq[j2][1].u = *(const uint4*)&SBc[(wc4 + 2 + j2) * 1024 + 512 + ro]; \
    }                                                                        \
    G_WRITE(SAn, SBn);                                                       \
    BARD(); LGKM0(); SB0();                                                  \
    __builtin_amdgcn_s_setprio(1);                                           \
    _Pragma("unroll")                                                        \
    for (int i2 = 0; i2 < 8; ++i2)                                           \
        _Pragma("unroll")                                                    \
        for (int j2 = 0; j2 < 2; ++j2) {                                     \
            acc[i2][2 + j2] = MF(A8[i2][0], Bq[j2][0], acc[i2][2 + j2]);     \
            acc[i2][2 + j2] = MF(A8[i2][1], Bq[j2][1], acc[i2][2 + j2]);     \
        }                                                                    \
    __builtin_amdgcn_s_setprio(0);                                           \
    BARD();                                                                  \
} while (0)

template<int KTOT>
__device__ __forceinline__ void gemm_core(
    const unsigned short* __restrict__ A, const unsigned short* __restrict__ B,
    int m0, int n0,
    unsigned short* sA0, unsigned short* sA1,
    unsigned short* sB0, unsigned short* sB1,
    floatx4 (&acc)[8][4]) {
    const int t = threadIdx.x;
    const int w = t >> 6, l = t & 63;
    const int lm = l & 15, quad = l >> 4;
    const int wr8 = (w >> 2) * 8, wc4 = (w & 3) * 4;
    // frag read slot (row=lm, chunk=quad)
    const int ro = ((lm & 3) | ((((lm >> 2) ^ quad) & 1) << 2) | (lm & 8)
                    | ((quad & 3) << 4)) * 8;
    // staging: lane -> (row ar, chunk c); write slot via same XOR map
    const int ar = l >> 2, c4 = l & 3;
    const int wo = ((ar & 3) | ((((ar >> 2) ^ c4) & 1) << 2) | (ar & 8)
                    | ((c4 & 3) << 4)) * 8;
    // per-wave staged groups: A rows {16w.., 16(w+8)..}, B rows same pattern
    const int gLo = w * 1024, gHi = (w + 8) * 1024;

    const unsigned short* AsrcLo = A + (size_t)(m0 + 16 * w + ar) * KTOT + c4 * 8;
    const unsigned short* AsrcHi = AsrcLo + (size_t)128 * KTOT;
    const unsigned short* BsrcLo = B + (size_t)(n0 + 16 * w + ar) * KTOT + c4 * 8;
    const unsigned short* BsrcHi = BsrcLo + (size_t)128 * KTOT;

    FragU A8[8][2], Bq[2][2];
    uint4 Ra0, Ra1, Ra2, Ra3, Rb0, Rb1, Rb2, Rb3;

    const int NS = KTOT / 64;

    // prologue: stage K-step 0 into buf0
    G_LOAD(0);
    G_WRITE(sA0, sB0);
    LGKM0();
    BARD();

    #pragma unroll 1
    for (int s = 0; s < NS; s += 2) {
        STEP(sA0, sB0, sA1, sB1, s);
        STEP(sA1, sB1, sA0, sB0, s + 1);
    }
}

// QKV projection: A=xb [8192][2048], B=wb [3072][2048] (Wq|Wk|Wv rows).
__global__ __launch_bounds__(512, 2)
void gemm_qkv256(const unsigned short* __restrict__ Ab, const unsigned short* __restrict__ Bb,
                 const float* __restrict__ bq, const float* __restrict__ bk,
                 const float* __restrict__ bv,
                 unsigned short* __restrict__ qo, unsigned short* __restrict__ ko,
                 unsigned short* __restrict__ vo) {
    __shared__ __align__(16) unsigned short sA[2][16384];
    __shared__ __align__(16) unsigned short sB[2][16384];

    // bijective XCD swizzle: 384 blocks = 8 XCDs x 48
    int id = blockIdx.y * 12 + blockIdx.x;
    id = (id & 7) * 48 + (id >> 3);
    const int m0 = (id / 12) * 256;
    const int n0 = (id % 12) * 256;

    floatx4 acc[8][4];
    #pragma unroll
    for (int i = 0; i < 8; ++i)
        #pragma unroll
        for (int j = 0; j < 4; ++j)
            acc[i][j] = (floatx4)(0.f);

    gemm_core<2048>(Ab, Bb, m0, n0, sA[0], sA[1], sB[0], sB[1], acc);

    const int t = threadIdx.x;
    const int w = t >> 6, l = t & 63;
    const int lm = l & 15, quad = l >> 4;
    const int wr = w >> 2, wc = w & 3;
    // each 256-col n-panel lies within one projection (1024 % 256 == 0)
    const int proj = n0 >> 10;
    unsigned short* Cb = proj == 0 ? qo : (proj == 1 ? ko : vo);
    const float* bias  = proj == 0 ? bq : (proj == 1 ? bk : bv);
    const int ndb = (n0 & 1023) + wc * 64;
    #pragma unroll
    for (int j = 0; j < 4; ++j) {
        const int d = ndb + j * 16 + lm;
        const float bj = bias[d];
        #pragma unroll
        for (int i = 0; i < 8; ++i) {
            const int row0 = m0 + wr * 128 + i * 16 + quad * 4;
            #pragma unroll
            for (int r = 0; r < 4; ++r)
                Cb[(size_t)(row0 + r) * 1024 + d] = f2bf(acc[i][j][r] + bj);
        }
    }
}

// Output projection: A=attn bf16 [8192][1024], B=wob [1024][1024]. fp32 out.
__global__ __launch_bounds__(512, 2)
void gemm_out256(const unsigned short* __restrict__ Ab, const unsigned short* __restrict__ Bb,
                 const float* __restrict__ bo, float* __restrict__ C) {
    __shared__ __align__(16) unsigned short sA[2][16384];
    __shared__ __align__(16) unsigned short sB[2][16384];

    // 128 blocks = 8 XCDs x 16, single full round on 256 CUs
    int id = blockIdx.y * 4 + blockIdx.x;
    id = (id & 7) * 16 + (id >> 3);
    const int m0 = (id / 4) * 256;
    const int n0 = (id % 4) * 256;

    floatx4 acc[8][4];
    #pragma unroll
    for (int i = 0; i < 8; ++i)
        #pragma unroll
        for (int j = 0; j < 4; ++j)
            acc[i][j] = (floatx4)(0.f);

    gemm_core<1024>(Ab, Bb, m0, n0, sA[0], sA[1], sB[0], sB[1], acc);

    const int t = threadIdx.x;
    const int w = t >> 6, l = t & 63;
    const int lm = l & 15, quad = l >> 4;
    const int wr = w >> 2, wc = w & 3;
    #pragma unroll
    for (int j = 0; j < 4; ++j) {
        const int col = n0 + wc * 64 + j * 16 + lm;
        const float bj = bo[col];
        #pragma unroll
        for (int i = 0; i < 8; ++i) {
            const int row0 = m0 + wr * 128 + i * 16 + quad * 4;
            #pragma unroll
            for (int r = 0; r < 4; ++r)
                C[(size_t)(row0 + r) * EE + col] = acc[i][j][r] + bj;
        }
    }
}

// ---- Stage 1 (MFMA): Sk[d][e] = sum_s sigma_k[s][d]*v[s][e], z[d]=colsum(sigma_k).
__global__ __launch_bounds__(256)
void seg_kv(const unsigned short* __restrict__ k, const unsigned short* __restrict__ v,
            float* __restrict__ Skv, float* __restrict__ zc) {
    __shared__ __align__(16) unsigned short KT[64 * 72];  // sigma_k^T [d][s]
    __shared__ __align__(16) unsigned short VT[64 * 72];  // v^T       [e][s]
    const int t = threadIdx.x;
    const int w = t >> 6, l = t & 63, quad = l >> 4, lm = l & 15;
    const size_t base = (size_t)blockIdx.x * 4096;

    #pragma unroll
    for (int i = 0; i < 2; ++i) {
        const int c  = t + i * 256;            // uint4 chunk
        const int sr = c >> 3, c0 = (c & 7) * 8;
        const uint4 pk = *(const uint4*)(k + base + c * 8);
        const uint4 pv = *(const uint4*)(v + base + c * 8);
        float4 f0, f1;
        unp8(pk, f0, f1);
        KT[(c0 + 0) * 72 + sr] = f2bf(elu1(f0.x));
        KT[(c0 + 1) * 72 + sr] = f2bf(elu1(f0.y));
        KT[(c0 + 2) * 72 + sr] = f2bf(elu1(f0.z));
        KT[(c0 + 3) * 72 + sr] = f2bf(elu1(f0.w));
        KT[(c0 + 4) * 72 + sr] = f2bf(elu1(f1.x));
        KT[(c0 + 5) * 72 + sr] = f2bf(elu1(f1.y));
        KT[(c0 + 6) * 72 + sr] = f2bf(elu1(f1.z));
        KT[(c0 + 7) * 72 + sr] = f2bf(elu1(f1.w));
        const unsigned short* pvs = (const unsigned short*)&pv;
        #pragma unroll
        for (int jj = 0; jj < 8; ++jj) VT[(c0 + jj) * 72 + sr] = pvs[jj];
    }
    __syncthreads();

    if (t < 64) {                                  // z[d] = rowsum of KT row d
        float ssum = 0.f;
        #pragma unroll
        for (int c2 = 0; c2 < 8; ++c2) {
            const uint4 p = *(const uint4*)&KT[t * 72 + c2 * 8];
            float4 a, b;
            unp8(p, a, b);
            ssum += a.x + a.y + a.z + a.w + b.x + b.y + b.z + b.w;
        }
        zc[(size_t)blockIdx.x * 64 + t] = ssum;
    }

    FragU ak0, ak1;
    ak0.u = *(const uint4*)&KT[(16 * w + lm) * 72 + quad * 8];
    ak1.u = *(const uint4*)&KT[(16 * w + lm) * 72 + 32 + quad * 8];
    floatx4 C4[4];
    #pragma unroll
    for (int j = 0; j < 4; ++j) C4[j] = (floatx4)(0.f);
    #pragma unroll
    for (int j = 0; j < 4; ++j) {
        FragU b0, b1;
        b0.u = *(const uint4*)&VT[(j * 16 + lm) * 72 + quad * 8];
        b1.u = *(const uint4*)&VT[(j * 16 + lm) * 72 + 32 + quad * 8];
        C4[j] = __builtin_amdgcn_mfma_f32_16x16x32_bf16(ak0.b, b0.b, C4[j], 0, 0, 0);
        C4[j] = __builtin_amdgcn_mfma_f32_16x16x32_bf16(ak1.b, b1.b, C4[j], 0, 0, 0);
    }
    const int d0 = 16 * w + quad * 4;
    #pragma unroll
    for (int j = 0; j < 4; ++j)
        #pragma unroll
        for (int r = 0; r < 4; ++r)
            Skv[base + (size_t)(d0 + r) * 64 + j * 16 + lm] = C4[j][r];
}

// ---- Stage 2: exclusive prefix over 16 segments per (b,h) chain.
__global__ __launch_bounds__(256)
void prefix_mem(float* __restrict__ Skv, float* __restrict__ zc) {
    const int t  = threadIdx.x;
    const int bh = blockIdx.y;
    float* p0 = Skv + (size_t)bh * 16 * 4096 + blockIdx.x * 512 + t * 2;
    float2 acc = make_float2(0.f, 0.f);
    #pragma unroll
    for (int n = 0; n < 16; ++n) {
        float2* p = (float2*)(p0 + (size_t)n * 4096);
        const float2 tmp = *p;
        *p = acc;
        acc.x += tmp.x; acc.y += tmp.y;
    }
    if (blockIdx.x == 0 && t < 64) {
        float* zp0 = zc + (size_t)bh * 16 * 64 + t;
        float za = 0.f;
        #pragma unroll
        for (int n = 0; n < 16; ++n) {
            float* zp = zp0 + n * 64;
            const float tmp = *zp;
            *zp = za;
            za += tmp;
        }
    }
}

// ---- Stage 3 (MFMA): per-segment attention.
__global__ __launch_bounds__(256)
void seg_attn(const unsigned short* __restrict__ q, const unsigned short* __restrict__ k,
              const unsigned short* __restrict__ v, const float* __restrict__ memp,
              const float* __restrict__ zp, const float* __restrict__ beta,
              unsigned short* __restrict__ ab) {
    __shared__ __align__(16) unsigned short Pb[64 * 72];  // P bf16 [s][t]
    __shared__ __align__(16) unsigned short VT[64 * 72];  // v^T    [e][s]
    __shared__ __align__(16) unsigned short MT[64 * 72];  // mem^T  [e][d]
    __shared__ float rs[64];
    __shared__ float zr[64];
    const int t = threadIdx.x;
    const int w = t >> 6, l = t & 63, quad = l >> 4, lm = l & 15;
    const int seg = blockIdx.x;
    const int h   = (seg >> 4) & 15;
    const float gate = 1.f / (1.f + __expf(-10.f * beta[h]));
    const float omg  = 1.f - gate;
    const size_t base = (size_t)seg * 4096;

    // stage v^T
    #pragma unroll
    for (int i = 0; i < 2; ++i) {
        const int c  = t + i * 256;
        const int sr = c >> 3, c0 = (c & 7) * 8;
        const uint4 pv = *(const uint4*)(v + base + c * 8);
        const unsigned short* pvs = (const unsigned short*)&pv;
        #pragma unroll
        for (int jj = 0; jj < 8; ++jj) VT[(c0 + jj) * 72 + sr] = pvs[jj];
    }
    // stage mem^T (fp32 -> bf16)
    #pragma unroll
    for (int i = 0; i < 4; ++i) {
        const int c = t + i * 256;               // float4 chunk
        const int d = c >> 4, e0 = (c & 15) * 4;
        const float4 m4 = *(const float4*)(memp + base + c * 4);
        MT[(e0 + 0) * 72 + d] = f2bf(m4.x);
        MT[(e0 + 1) * 72 + d] = f2bf(m4.y);
        MT[(e0 + 2) * 72 + d] = f2bf(m4.z);
        MT[(e0 + 3) * 72 + d] = f2bf(m4.w);
    }
    // rs[s] = rowsum(sigma_q): quarter-row per thread + shfl reduce
    {
        const int s = t >> 2, dq = (t & 3) * 16;
        const uint4 a0 = *(const uint4*)(q + base + s * 64 + dq);
        const uint4 a1 = *(const uint4*)(q + base + s * 64 + dq + 8);
        float4 f0, f1, f2, f3;
        unp8(a0, f0, f1); unp8(a1, f2, f3);
        float p = elu1(f0.x) + elu1(f0.y) + elu1(f0.z) + elu1(f0.w)
                + elu1(f1.x) + elu1(f1.y) + elu1(f1.z) + elu1(f1.w)
                + elu1(f2.x) + elu1(f2.y) + elu1(f2.z) + elu1(f2.w)
                + elu1(f3.x) + elu1(f3.y) + elu1(f3.z) + elu1(f3.w);
        p += __shfl_xor(p, 1, 64);
        p += __shfl_xor(p, 2, 64);
        if ((t & 3) == 0) rs[s] = p;
    }
    if (t < 64) zr[t] = zp[(size_t)seg * 64 + t];
    __syncthreads();

    // ---- scores: wave w computes rows [16w,16w+16) x all 64 cols
    const unsigned short* qrow = q + base + (size_t)(16 * w + lm) * 64;
    FragU aq0, aq1;
    aq0.u = *(const uint4*)(qrow + quad * 8);
    aq1.u = *(const uint4*)(qrow + 32 + quad * 8);
    floatx4 S[4];
    #pragma unroll
    for (int j = 0; j < 4; ++j) S[j] = (floatx4)(0.f);
    #pragma unroll
    for (int j = 0; j < 4; ++j) {
        const unsigned short* krow = k + base + (size_t)(j * 16 + lm) * 64;
        FragU b0, b1;
        b0.u = *(const uint4*)(krow + quad * 8);
        b1.u = *(const uint4*)(krow + 32 + quad * 8);
        S[j] = __builtin_amdgcn_mfma_f32_16x16x32_bf16(aq0.b, b0.b, S[j], 0, 0, 0);
        S[j] = __builtin_amdgcn_mfma_f32_16x16x32_bf16(aq1.b, b1.b, S[j], 0, 0, 0);
    }
    // ---- causal softmax in C-layout registers; write P bf16 to LDS
    const int srow0 = 16 * w + quad * 4;
    #pragma unroll
    for (int r = 0; r < 4; ++r) {
        const int s_g = srow0 + r;
        float m = -3.0e38f;
        #pragma unroll
        for (int j = 0; j < 4; ++j) {
            const int t_g = j * 16 + lm;
            const float val = (t_g <= s_g) ? S[j][r] * 0.125f : -3.0e38f;
            S[j][r] = val;
            m = fmaxf(m, val);
        }
        m = fmaxf(m, __shfl_xor(m, 1, 64));
        m = fmaxf(m, __shfl_xor(m, 2, 64));
        m = fmaxf(m, __shfl_xor(m, 4, 64));
        m = fmaxf(m, __shfl_xor(m, 8, 64));
        float ss = 0.f;
        #pragma unroll
        for (int j = 0; j < 4; ++j) {
            const int t_g = j * 16 + lm;
            const float e = (t_g <= s_g) ? __expf(S[j][r] - m) : 0.f;
            S[j][r] = e;
            ss += e;
        }
        ss += __shfl_xor(ss, 1, 64);
        ss += __shfl_xor(ss, 2, 64);
        ss += __shfl_xor(ss, 4, 64);
        ss += __shfl_xor(ss, 8, 64);
        const float inv = 1.f / ss;
        #pragma unroll
        for (int j = 0; j < 4; ++j)
            Pb[s_g * 72 + j * 16 + lm] = f2bf(S[j][r] * inv);
    }
    __syncthreads();

    // ---- A_dot = P@V and A_mem = sigma_q@mem (both C-layout accumulators)
    FragU ap0, ap1, as0, as1;
    ap0.u = *(const uint4*)&Pb[(16 * w + lm) * 72 + quad * 8];
    ap1.u = *(const uint4*)&Pb[(16 * w + lm) * 72 + 32 + quad * 8];
    {
        float4 f0, f1, f2, f3;
        unp8(aq0.u, f0, f1);
        unp8(aq1.u, f2, f3);
        f0.x = elu1(f0.x); f0.y = elu1(f0.y); f0.z = elu1(f0.z); f0.w = elu1(f0.w);
        f1.x = elu1(f1.x); f1.y = elu1(f1.y); f1.z = elu1(f1.z); f1.w = elu1(f1.w);
        f2.x = elu1(f2.x); f2.y = elu1(f2.y); f2.z = elu1(f2.z); f2.w = elu1(f2.w);
        f3.x = elu1(f3.x); f3.y = elu1(f3.y); f3.z = elu1(f3.z); f3.w = elu1(f3.w);
        as0.u = pack8bf(f0, f1);
        as1.u = pack8bf(f2, f3);
    }
    floatx4 AD[4], AM[4];
    #pragma unroll
    for (int j = 0; j < 4; ++j) { AD[j] = (floatx4)(0.f); AM[j] = (floatx4)(0.f); }
    #pragma unroll
    for (int j = 0; j < 4; ++j) {
        FragU bv0, bv1, bm0, bm1;
        bv0.u = *(const uint4*)&VT[(j * 16 + lm) * 72 + quad * 8];
        bv1.u = *(const uint4*)&VT[(j * 16 + lm) * 72 + 32 + quad * 8];
        bm0.u = *(const uint4*)&MT[(j * 16 + lm) * 72 + quad * 8];
        bm1.u = *(const uint4*)&MT[(j * 16 + lm) * 72 + 32 + quad * 8];
        AD[j] = __builtin_amdgcn_mfma_f32_16x16x32_bf16(ap0.b, bv0.b, AD[j], 0, 0, 0);
        AD[j] = __builtin_amdgcn_mfma_f32_16x16x32_bf16(ap1.b, bv1.b, AD[j], 0, 0, 0);
        AM[j] = __builtin_amdgcn_mfma_f32_16x16x32_bf16(as0.b, bm0.b, AM[j], 0, 0, 0);
        AM[j] = __builtin_amdgcn_mfma_f32_16x16x32_bf16(as1.b, bm1.b, AM[j], 0, 0, 0);
    }
    // ---- combine + store attn bf16
    #pragma unroll
    for (int j = 0; j < 4; ++j) {
        const int d = j * 16 + lm;
        const float zd = zr[d];
        #pragma unroll
        for (int r = 0; r < 4; ++r) {
            const int s_g = srow0 + r;
            const float den = rs[s_g] * zd + 1e-6f;
            const float o = gate * (AM[j][r] / den) + omg * AD[j][r];
            ab[base + (size_t)s_g * 64 + d] = f2bf(o);
        }
    }
}

extern "C" void kernel_launch(void* const* d_in, const int* in_sizes, int n_in,
                              void* d_out, int out_size, void* d_ws, size_t ws_size,
                              hipStream_t stream) {
    const float* x    = (const float*)d_in[0];
    const float* Wq   = (const float*)d_in[1];
    const float* bq   = (const float*)d_in[2];
    const float* Wk   = (const float*)d_in[3];
    const float* bk   = (const float*)d_in[4];
    const float* Wv   = (const float*)d_in[5];
    const float* bv   = (const float*)d_in[6];
    const float* Wo   = (const float*)d_in[7];
    const float* bo   = (const float*)d_in[8];
    const float* beta = (const float*)d_in[9];
    float* out = (float*)d_out;

    unsigned char* wsb = (unsigned char*)d_ws;
    unsigned short* xb  = (unsigned short*)(wsb);                       // 32 MB; reused as ab
    unsigned short* wb  = (unsigned short*)(wsb + (32ull << 20));       // 12 MB  [3072][2048]
    unsigned short* wob = (unsigned short*)(wsb + (44ull << 20));       // 2 MB   [1024][1024]
    unsigned short* qb  = (unsigned short*)(wsb + (46ull << 20));       // 16 MB
    unsigned short* kb  = (unsigned short*)(wsb + (62ull << 20));       // 16 MB
    unsigned short* vb  = (unsigned short*)(wsb + (78ull << 20));       // 16 MB
    float* Skv = (float*)(wsb + (94ull << 20));                         // 32 MB
    float* zc  = (float*)(wsb + (126ull << 20));                        // 0.5 MB
    unsigned short* ab = xb;   // attn bf16 (xb dead after gemm_qkv)

    cvt_bf16<<<8192, 256, 0, stream>>>(x, xb, 2097152);
    cvt_w<<<3584, 256, 0, stream>>>(Wq, Wk, Wv, Wo, wb, wob);

    gemm_qkv256<<<dim3(12, 32), 512, 0, stream>>>(xb, wb, bq, bk, bv, qb, kb, vb);
    seg_kv<<<2048, 256, 0, stream>>>(kb, vb, Skv, zc);
    prefix_mem<<<dim3(8, 128), 256, 0, stream>>>(Skv, zc);
    seg_attn<<<2048, 256, 0, stream>>>(qb, kb, vb, Skv, zc, beta, ab);
    gemm_out256<<<dim3(4, 32), 512, 0, stream>>>(ab, wob, bo, out);
}

// Round 5
// 418.972 us; speedup vs baseline: 1.0129x; 1.0129x over previous
//
#include <hip/hip_runtime.h>
#include <hip/hip_bf16.h>
#include <cstddef>

#define EE 1024            // E
#define MTOT 8192          // B*E

using floatx4 = __attribute__((ext_vector_type(4))) float;
using bf16x8  = __attribute__((ext_vector_type(8))) __bf16;

union FragU { uint4 u; bf16x8 b; };

__device__ __forceinline__ float elu1(float x) {
    return x > 0.f ? x + 1.f : __expf(x);
}

__device__ __forceinline__ unsigned int pack2bf(float x, float y) {
    __hip_bfloat162 h = __float22bfloat162_rn(make_float2(x, y));
    union { __hip_bfloat162 h; unsigned int u; } c;
    c.h = h;
    return c.u;
}

__device__ __forceinline__ uint4 pack8bf(const float4 a, const float4 b) {
    uint4 r;
    r.x = pack2bf(a.x, a.y); r.y = pack2bf(a.z, a.w);
    r.z = pack2bf(b.x, b.y); r.w = pack2bf(b.z, b.w);
    return r;
}

__device__ __forceinline__ unsigned short f2bf(float x) {
    union { __hip_bfloat16 h; unsigned short s; } c;
    c.h = __float2bfloat16(x);
    return c.s;
}

__device__ __forceinline__ void unp8(const uint4 p, float4& a, float4& b) {
    a.x = __uint_as_float(p.x << 16); a.y = __uint_as_float(p.x & 0xffff0000u);
    a.z = __uint_as_float(p.y << 16); a.w = __uint_as_float(p.y & 0xffff0000u);
    b.x = __uint_as_float(p.z << 16); b.y = __uint_as_float(p.z & 0xffff0000u);
    b.z = __uint_as_float(p.w << 16); b.w = __uint_as_float(p.w & 0xffff0000u);
}

// fp32 -> bf16 bulk convert, 8 elems/thread
__global__ __launch_bounds__(256)
void cvt_bf16(const float* __restrict__ src, unsigned short* __restrict__ dst, int n8) {
    const int i = blockIdx.x * 256 + threadIdx.x;
    if (i >= n8) return;
    const float4 a = ((const float4*)src)[2 * i];
    const float4 b = ((const float4*)src)[2 * i + 1];
    ((uint4*)dst)[i] = pack8bf(a, b);
}

// All four weight matrices in one launch.
__global__ __launch_bounds__(256)
void cvt_w(const float* __restrict__ Wq, const float* __restrict__ Wk,
           const float* __restrict__ Wv, const float* __restrict__ Wo,
           unsigned short* __restrict__ wb, unsigned short* __restrict__ wob) {
    const int i = blockIdx.x * 256 + threadIdx.x;
    if (i >= 917504) return;
    const float* src;
    unsigned short* dst;
    int off;
    if (i < 262144)      { src = Wq; dst = wb;           off = i; }
    else if (i < 524288) { src = Wk; dst = wb + 2097152; off = i - 262144; }
    else if (i < 786432) { src = Wv; dst = wb + 4194304; off = i - 524288; }
    else                 { src = Wo; dst = wob;          off = i - 786432; }
    const float4 a = ((const float4*)src)[2 * off];
    const float4 b = ((const float4*)src)[2 * off + 1];
    ((uint4*)dst)[off] = pack8bf(a, b);
}

// ============================================================================
// 256x256 reg-staged GEMM core. A[M][K] bf16, B[N][K]^T bf16 (row-major B^T).
// 8 waves (2m x 4n), per-wave 128x64 output, BK=64, double-buffered 128 KiB LDS.
//
// LDS: per tile, 16 row-groups of 16 rows; per (group, k-half) a 64-slot
// space of 16B chunks. Slot for (row r, chunk c):
//   slot(r,c) = ((r + 2c) & 7) | (r & 8) | (c << 4)
// ds_*_b128 conflict granularity is the OCTET (8 lanes x 16B = 128B = all 32
// banks) [derived from r2 (linear = 0 conflicts), r3 (4-way), r4 (2-way)]:
//   read octet  (c fixed, r=0..7 / 8..15): slot&7 = (r+2c)&7 -> 8 distinct
//     bank-groups -> conflict-free.
//   write octet (r=2k,2k+1; c=0..3): (2k+{0,2,4,6})&7 = evens, (2k+1+...)&7
//     = odds -> all 8 bank-groups -> conflict-free.   (r4's map collided
//     slot0/32 and 20/52 within write octets -> the measured 1.59e7.)
// Bijective: c = bits4-5, r3 = bit3, r_low3 = (low3 - 2c) & 7.
//
// Staging: depth-1 reg pipeline (T14 split). Phase L: issue 8 coalesced
// global_load_dwordx4 for K-step s+1 FIRST (max issue->consume distance:
// ds-read cluster + MFMA-L + barrier > HBM latency), then ds_read A(16)+
// Blow(4); barrier; lgkm0; 32 MFMA. Phase H: ds_read Bhigh(4); ds_write the
// staged regs (auto-exact vmcnt) into the other buffer; barrier; lgkm0;
// 32 MFMA. All loads register-tracked; nothing in flight at endpgm.
// ============================================================================

#define BARD()  __builtin_amdgcn_s_barrier()
#define LGKM0() asm volatile("s_waitcnt lgkmcnt(0)" ::: "memory")
#define SB0()   __builtin_amdgcn_sched_barrier(0)
#define MF(va, vb, c) __builtin_amdgcn_mfma_f32_16x16x32_bf16((va).b, (vb).b, c, 0, 0, 0)

#define G_LOAD(KS) do {                                                      \
    const size_t ko_ = (size_t)(KS) * 64;                                    \
    Ra0 = *(const uint4*)(AsrcLo + ko_); Ra1 = *(const uint4*)(AsrcLo + ko_ + 32); \
    Ra2 = *(const uint4*)(AsrcHi + ko_); Ra3 = *(const uint4*)(AsrcHi + ko_ + 32); \
    Rb0 = *(const uint4*)(BsrcLo + ko_); Rb1 = *(const uint4*)(BsrcLo + ko_ + 32); \
    Rb2 = *(const uint4*)(BsrcHi + ko_); Rb3 = *(const uint4*)(BsrcHi + ko_ + 32); \
} while (0)

#define G_WRITE(SAp, SBp) do {                                               \
    *(uint4*)&SAp[gLo + wo]       = Ra0; *(uint4*)&SAp[gLo + 512 + wo] = Ra1; \
    *(uint4*)&SAp[gHi + wo]       = Ra2; *(uint4*)&SAp[gHi + 512 + wo] = Ra3; \
    *(uint4*)&SBp[gLo + wo]       = Rb0; *(uint4*)&SBp[gLo + 512 + wo] = Rb1; \
    *(uint4*)&SBp[gHi + wo]       = Rb2; *(uint4*)&SBp[gHi + 512 + wo] = Rb3; \
} while (0)

#define STEP(SAc, SBc, SAn, SBn, S) do {                                     \
    { const int kn_ = ((S) + 1 < NS) ? (S) + 1 : NS - 1; G_LOAD(kn_); }      \
    _Pragma("unroll")                                                        \
    for (int i2 = 0; i2 < 8; ++i2) {                                         \
        A8[i2][0].u = *(const uint4*)&SAc[(wr8 + i2) * 1024 + ro];           \
        A8[i2][1].u = *(const uint4*)&SAc[(wr8 + i2) * 1024 + 512 + ro];     \
    }                                                                        \
    _Pragma("unroll")                                                        \
    for (int j2 = 0; j2 < 2; ++j2) {                                         \
        Bq[j2][0].u = *(const uint4*)&SBc[(wc4 + j2) * 1024 + ro];           \
        Bq[j2][1].u = *(const uint4*)&SBc[(wc4 + j2) * 1024 + 512 + ro];     \
    }                                                                        \
    BARD(); LGKM0(); SB0();                                                  \
    __builtin_amdgcn_s_setprio(1);                                           \
    _Pragma("unroll")                                                        \
    for (int i2 = 0; i2 < 8; ++i2)                                           \
        _Pragma("unroll")                                                    \
        for (int j2 = 0; j2 < 2; ++j2) {                                     \
            acc[i2][j2] = MF(A8[i2][0], Bq[j2][0], acc[i2][j2]);             \
            acc[i2][j2] = MF(A8[i2][1], Bq[j2][1], acc[i2][j2]);             \
        }                                                                    \
    __builtin_amdgcn_s_setprio(0);                                           \
    BARD();                                                                  \
    _Pragma("unroll")                                                        \
    for (int j2 = 0; j2 < 2; ++j2) {                                         \
        Bq[j2][0].u = *(const uint4*)&SBc[(wc4 + 2 + j2) * 1024 + ro];       \
        Bq[j2][1].u = *(const uint4*)&SBc[(wc4 + 2 + j2) * 1024 + 512 + ro]; \
    }                                                                        \
    G_WRITE(SAn, SBn);                                                       \
    BARD(); LGKM0(); SB0();                                                  \
    __builtin_amdgcn_s_setprio(1);                                           \
    _Pragma("unroll")                                                        \
    for (int i2 = 0; i2 < 8; ++i2)                                           \
        _Pragma("unroll")                                                    \
        for (int j2 = 0; j2 < 2; ++j2) {                                     \
            acc[i2][2 + j2] = MF(A8[i2][0], Bq[j2][0], acc[i2][2 + j2]);     \
            acc[i2][2 + j2] = MF(A8[i2][1], Bq[j2][1], acc[i2][2 + j2]);     \
        }                                                                    \
    __builtin_amdgcn_s_setprio(0);                                           \
    BARD();                                                                  \
} while (0)

template<int KTOT>
__device__ __forceinline__ void gemm_core(
    const unsigned short* __restrict__ A, const unsigned short* __restrict__ B,
    int m0, int n0,
    unsigned short* sA0, unsigned short* sA1,
    unsigned short* sB0, unsigned short* sB1,
    floatx4 (&acc)[8][4]) {
    const int t = threadIdx.x;
    const int w = t >> 6, l = t & 63;
    const int lm = l & 15, quad = l >> 4;
    const int wr8 = (w >> 2) * 8, wc4 = (w & 3) * 4;
    // frag read slot (row=lm, chunk=quad): octet-tiling XOR map
    const int ro = (((lm + 2 * quad) & 7) | (lm & 8) | (quad << 4)) * 8;
    // staging: lane -> (row ar, chunk c4); same slot map
    const int ar = l >> 2, c4 = l & 3;
    const int wo = (((ar + 2 * c4) & 7) | (ar & 8) | (c4 << 4)) * 8;
    // per-wave staged groups: rows {16w..}, {16(w+8)..}
    const int gLo = w * 1024, gHi = (w + 8) * 1024;

    const unsigned short* AsrcLo = A + (size_t)(m0 + 16 * w + ar) * KTOT + c4 * 8;
    const unsigned short* AsrcHi = AsrcLo + (size_t)128 * KTOT;
    const unsigned short* BsrcLo = B + (size_t)(n0 + 16 * w + ar) * KTOT + c4 * 8;
    const unsigned short* BsrcHi = BsrcLo + (size_t)128 * KTOT;

    FragU A8[8][2], Bq[2][2];
    uint4 Ra0, Ra1, Ra2, Ra3, Rb0, Rb1, Rb2, Rb3;

    const int NS = KTOT / 64;

    // prologue: stage K-step 0 into buf0
    G_LOAD(0);
    G_WRITE(sA0, sB0);
    LGKM0();
    BARD();

    #pragma unroll 1
    for (int s = 0; s < NS; s += 2) {
        STEP(sA0, sB0, sA1, sB1, s);
        STEP(sA1, sB1, sA0, sB0, s + 1);
    }
}

// QKV projection: A=xb [8192][2048], B=wb [3072][2048] (Wq|Wk|Wv rows).
__global__ __launch_bounds__(512, 2)
void gemm_qkv256(const unsigned short* __restrict__ Ab, const unsigned short* __restrict__ Bb,
                 const float* __restrict__ bq, const float* __restrict__ bk,
                 const float* __restrict__ bv,
                 unsigned short* __restrict__ qo, unsigned short* __restrict__ ko,
                 unsigned short* __restrict__ vo) {
    __shared__ __align__(16) unsigned short sA[2][16384];
    __shared__ __align__(16) unsigned short sB[2][16384];

    // bijective XCD swizzle: 384 blocks = 8 XCDs x 48
    int id = blockIdx.y * 12 + blockIdx.x;
    id = (id & 7) * 48 + (id >> 3);
    const int m0 = (id / 12) * 256;
    const int n0 = (id % 12) * 256;

    floatx4 acc[8][4];
    #pragma unroll
    for (int i = 0; i < 8; ++i)
        #pragma unroll
        for (int j = 0; j < 4; ++j)
            acc[i][j] = (floatx4)(0.f);

    gemm_core<2048>(Ab, Bb, m0, n0, sA[0], sA[1], sB[0], sB[1], acc);

    const int t = threadIdx.x;
    const int w = t >> 6, l = t & 63;
    const int lm = l & 15, quad = l >> 4;
    const int wr = w >> 2, wc = w & 3;
    // each 256-col n-panel lies within one projection (1024 % 256 == 0)
    const int proj = n0 >> 10;
    unsigned short* Cb = proj == 0 ? qo : (proj == 1 ? ko : vo);
    const float* bias  = proj == 0 ? bq : (proj == 1 ? bk : bv);
    const int ndb = (n0 & 1023) + wc * 64;
    #pragma unroll
    for (int j = 0; j < 4; ++j) {
        const int d = ndb + j * 16 + lm;
        const float bj = bias[d];
        #pragma unroll
        for (int i = 0; i < 8; ++i) {
            const int row0 = m0 + wr * 128 + i * 16 + quad * 4;
            #pragma unroll
            for (int r = 0; r < 4; ++r)
                Cb[(size_t)(row0 + r) * 1024 + d] = f2bf(acc[i][j][r] + bj);
        }
    }
}

// Output projection: A=attn bf16 [8192][1024], B=wob [1024][1024]. fp32 out.
__global__ __launch_bounds__(512, 2)
void gemm_out256(const unsigned short* __restrict__ Ab, const unsigned short* __restrict__ Bb,
                 const float* __restrict__ bo, float* __restrict__ C) {
    __shared__ __align__(16) unsigned short sA[2][16384];
    __shared__ __align__(16) unsigned short sB[2][16384];

    // 128 blocks = 8 XCDs x 16, single round on 256 CUs
    int id = blockIdx.y * 4 + blockIdx.x;
    id = (id & 7) * 16 + (id >> 3);
    const int m0 = (id / 4) * 256;
    const int n0 = (id % 4) * 256;

    floatx4 acc[8][4];
    #pragma unroll
    for (int i = 0; i < 8; ++i)
        #pragma unroll
        for (int j = 0; j < 4; ++j)
            acc[i][j] = (floatx4)(0.f);

    gemm_core<1024>(Ab, Bb, m0, n0, sA[0], sA[1], sB[0], sB[1], acc);

    const int t = threadIdx.x;
    const int w = t >> 6, l = t & 63;
    const int lm = l & 15, quad = l >> 4;
    const int wr = w >> 2, wc = w & 3;
    #pragma unroll
    for (int j = 0; j < 4; ++j) {
        const int col = n0 + wc * 64 + j * 16 + lm;
        const float bj = bo[col];
        #pragma unroll
        for (int i = 0; i < 8; ++i) {
            const int row0 = m0 + wr * 128 + i * 16 + quad * 4;
            #pragma unroll
            for (int r = 0; r < 4; ++r)
                C[(size_t)(row0 + r) * EE + col] = acc[i][j][r] + bj;
        }
    }
}

// ---- Stage 1 (MFMA): Sk[d][e] = sum_s sigma_k[s][d]*v[s][e], z[d]=colsum(sigma_k).
__global__ __launch_bounds__(256)
void seg_kv(const unsigned short* __restrict__ k, const unsigned short* __restrict__ v,
            float* __restrict__ Skv, float* __restrict__ zc) {
    __shared__ __align__(16) unsigned short KT[64 * 72];  // sigma_k^T [d][s]
    __shared__ __align__(16) unsigned short VT[64 * 72];  // v^T       [e][s]
    const int t = threadIdx.x;
    const int w = t >> 6, l = t & 63, quad = l >> 4, lm = l & 15;
    const size_t base = (size_t)blockIdx.x * 4096;

    #pragma unroll
    for (int i = 0; i < 2; ++i) {
        const int c  = t + i * 256;            // uint4 chunk
        const int sr = c >> 3, c0 = (c & 7) * 8;
        const uint4 pk = *(const uint4*)(k + base + c * 8);
        const uint4 pv = *(const uint4*)(v + base + c * 8);
        float4 f0, f1;
        unp8(pk, f0, f1);
        KT[(c0 + 0) * 72 + sr] = f2bf(elu1(f0.x));
        KT[(c0 + 1) * 72 + sr] = f2bf(elu1(f0.y));
        KT[(c0 + 2) * 72 + sr] = f2bf(elu1(f0.z));
        KT[(c0 + 3) * 72 + sr] = f2bf(elu1(f0.w));
        KT[(c0 + 4) * 72 + sr] = f2bf(elu1(f1.x));
        KT[(c0 + 5) * 72 + sr] = f2bf(elu1(f1.y));
        KT[(c0 + 6) * 72 + sr] = f2bf(elu1(f1.z));
        KT[(c0 + 7) * 72 + sr] = f2bf(elu1(f1.w));
        const unsigned short* pvs = (const unsigned short*)&pv;
        #pragma unroll
        for (int jj = 0; jj < 8; ++jj) VT[(c0 + jj) * 72 + sr] = pvs[jj];
    }
    __syncthreads();

    if (t < 64) {                                  // z[d] = rowsum of KT row d
        float ssum = 0.f;
        #pragma unroll
        for (int c2 = 0; c2 < 8; ++c2) {
            const uint4 p = *(const uint4*)&KT[t * 72 + c2 * 8];
            float4 a, b;
            unp8(p, a, b);
            ssum += a.x + a.y + a.z + a.w + b.x + b.y + b.z + b.w;
        }
        zc[(size_t)blockIdx.x * 64 + t] = ssum;
    }

    FragU ak0, ak1;
    ak0.u = *(const uint4*)&KT[(16 * w + lm) * 72 + quad * 8];
    ak1.u = *(const uint4*)&KT[(16 * w + lm) * 72 + 32 + quad * 8];
    floatx4 C4[4];
    #pragma unroll
    for (int j = 0; j < 4; ++j) C4[j] = (floatx4)(0.f);
    #pragma unroll
    for (int j = 0; j < 4; ++j) {
        FragU b0, b1;
        b0.u = *(const uint4*)&VT[(j * 16 + lm) * 72 + quad * 8];
        b1.u = *(const uint4*)&VT[(j * 16 + lm) * 72 + 32 + quad * 8];
        C4[j] = __builtin_amdgcn_mfma_f32_16x16x32_bf16(ak0.b, b0.b, C4[j], 0, 0, 0);
        C4[j] = __builtin_amdgcn_mfma_f32_16x16x32_bf16(ak1.b, b1.b, C4[j], 0, 0, 0);
    }
    const int d0 = 16 * w + quad * 4;
    #pragma unroll
    for (int j = 0; j < 4; ++j)
        #pragma unroll
        for (int r = 0; r < 4; ++r)
            Skv[base + (size_t)(d0 + r) * 64 + j * 16 + lm] = C4[j][r];
}

// ---- Stage 2: exclusive prefix over 16 segments per (b,h) chain.
__global__ __launch_bounds__(256)
void prefix_mem(float* __restrict__ Skv, float* __restrict__ zc) {
    const int t  = threadIdx.x;
    const int bh = blockIdx.y;
    float* p0 = Skv + (size_t)bh * 16 * 4096 + blockIdx.x * 512 + t * 2;
    float2 acc = make_float2(0.f, 0.f);
    #pragma unroll
    for (int n = 0; n < 16; ++n) {
        float2* p = (float2*)(p0 + (size_t)n * 4096);
        const float2 tmp = *p;
        *p = acc;
        acc.x += tmp.x; acc.y += tmp.y;
    }
    if (blockIdx.x == 0 && t < 64) {
        float* zp0 = zc + (size_t)bh * 16 * 64 + t;
        float za = 0.f;
        #pragma unroll
        for (int n = 0; n < 16; ++n) {
            float* zp = zp0 + n * 64;
            const float tmp = *zp;
            *zp = za;
            za += tmp;
        }
    }
}

// ---- Stage 3 (MFMA): per-segment attention.
__global__ __launch_bounds__(256)
void seg_attn(const unsigned short* __restrict__ q, const unsigned short* __restrict__ k,
              const unsigned short* __restrict__ v, const float* __restrict__ memp,
              const float* __restrict__ zp, const float* __restrict__ beta,
              unsigned short* __restrict__ ab) {
    __shared__ __align__(16) unsigned short Pb[64 * 72];  // P bf16 [s][t]
    __shared__ __align__(16) unsigned short VT[64 * 72];  // v^T    [e][s]
    __shared__ __align__(16) unsigned short MT[64 * 72];  // mem^T  [e][d]
    __shared__ float rs[64];
    __shared__ float zr[64];
    const int t = threadIdx.x;
    const int w = t >> 6, l = t & 63, quad = l >> 4, lm = l & 15;
    const int seg = blockIdx.x;
    const int h   = (seg >> 4) & 15;
    const float gate = 1.f / (1.f + __expf(-10.f * beta[h]));
    const float omg  = 1.f - gate;
    const size_t base = (size_t)seg * 4096;

    // stage v^T
    #pragma unroll
    for (int i = 0; i < 2; ++i) {
        const int c  = t + i * 256;
        const int sr = c >> 3, c0 = (c & 7) * 8;
        const uint4 pv = *(const uint4*)(v + base + c * 8);
        const unsigned short* pvs = (const unsigned short*)&pv;
        #pragma unroll
        for (int jj = 0; jj < 8; ++jj) VT[(c0 + jj) * 72 + sr] = pvs[jj];
    }
    // stage mem^T (fp32 -> bf16)
    #pragma unroll
    for (int i = 0; i < 4; ++i) {
        const int c = t + i * 256;               // float4 chunk
        const int d = c >> 4, e0 = (c & 15) * 4;
        const float4 m4 = *(const float4*)(memp + base + c * 4);
        MT[(e0 + 0) * 72 + d] = f2bf(m4.x);
        MT[(e0 + 1) * 72 + d] = f2bf(m4.y);
        MT[(e0 + 2) * 72 + d] = f2bf(m4.z);
        MT[(e0 + 3) * 72 + d] = f2bf(m4.w);
    }
    // rs[s] = rowsum(sigma_q): quarter-row per thread + shfl reduce
    {
        const int s = t >> 2, dq = (t & 3) * 16;
        const uint4 a0 = *(const uint4*)(q + base + s * 64 + dq);
        const uint4 a1 = *(const uint4*)(q + base + s * 64 + dq + 8);
        float4 f0, f1, f2, f3;
        unp8(a0, f0, f1); unp8(a1, f2, f3);
        float p = elu1(f0.x) + elu1(f0.y) + elu1(f0.z) + elu1(f0.w)
                + elu1(f1.x) + elu1(f1.y) + elu1(f1.z) + elu1(f1.w)
                + elu1(f2.x) + elu1(f2.y) + elu1(f2.z) + elu1(f2.w)
                + elu1(f3.x) + elu1(f3.y) + elu1(f3.z) + elu1(f3.w);
        p += __shfl_xor(p, 1, 64);
        p += __shfl_xor(p, 2, 64);
        if ((t & 3) == 0) rs[s] = p;
    }
    if (t < 64) zr[t] = zp[(size_t)seg * 64 + t];
    __syncthreads();

    // ---- scores: wave w computes rows [16w,16w+16) x all 64 cols
    const unsigned short* qrow = q + base + (size_t)(16 * w + lm) * 64;
    FragU aq0, aq1;
    aq0.u = *(const uint4*)(qrow + quad * 8);
    aq1.u = *(const uint4*)(qrow + 32 + quad * 8);
    floatx4 S[4];
    #pragma unroll
    for (int j = 0; j < 4; ++j) S[j] = (floatx4)(0.f);
    #pragma unroll
    for (int j = 0; j < 4; ++j) {
        const unsigned short* krow = k + base + (size_t)(j * 16 + lm) * 64;
        FragU b0, b1;
        b0.u = *(const uint4*)(krow + quad * 8);
        b1.u = *(const uint4*)(krow + 32 + quad * 8);
        S[j] = __builtin_amdgcn_mfma_f32_16x16x32_bf16(aq0.b, b0.b, S[j], 0, 0, 0);
        S[j] = __builtin_amdgcn_mfma_f32_16x16x32_bf16(aq1.b, b1.b, S[j], 0, 0, 0);
    }
    // ---- causal softmax in C-layout registers; write P bf16 to LDS
    const int srow0 = 16 * w + quad * 4;
    #pragma unroll
    for (int r = 0; r < 4; ++r) {
        const int s_g = srow0 + r;
        float m = -3.0e38f;
        #pragma unroll
        for (int j = 0; j < 4; ++j) {
            const int t_g = j * 16 + lm;
            const float val = (t_g <= s_g) ? S[j][r] * 0.125f : -3.0e38f;
            S[j][r] = val;
            m = fmaxf(m, val);
        }
        m = fmaxf(m, __shfl_xor(m, 1, 64));
        m = fmaxf(m, __shfl_xor(m, 2, 64));
        m = fmaxf(m, __shfl_xor(m, 4, 64));
        m = fmaxf(m, __shfl_xor(m, 8, 64));
        float ss = 0.f;
        #pragma unroll
        for (int j = 0; j < 4; ++j) {
            const int t_g = j * 16 + lm;
            const float e = (t_g <= s_g) ? __expf(S[j][r] - m) : 0.f;
            S[j][r] = e;
            ss += e;
        }
        ss += __shfl_xor(ss, 1, 64);
        ss += __shfl_xor(ss, 2, 64);
        ss += __shfl_xor(ss, 4, 64);
        ss += __shfl_xor(ss, 8, 64);
        const float inv = 1.f / ss;
        #pragma unroll
        for (int j = 0; j < 4; ++j)
            Pb[s_g * 72 + j * 16 + lm] = f2bf(S[j][r] * inv);
    }
    __syncthreads();

    // ---- A_dot = P@V and A_mem = sigma_q@mem (both C-layout accumulators)
    FragU ap0, ap1, as0, as1;
    ap0.u = *(const uint4*)&Pb[(16 * w + lm) * 72 + quad * 8];
    ap1.u = *(const uint4*)&Pb[(16 * w + lm) * 72 + 32 + quad * 8];
    {
        float4 f0, f1, f2, f3;
        unp8(aq0.u, f0, f1);
        unp8(aq1.u, f2, f3);
        f0.x = elu1(f0.x); f0.y = elu1(f0.y); f0.z = elu1(f0.z); f0.w = elu1(f0.w);
        f1.x = elu1(f1.x); f1.y = elu1(f1.y); f1.z = elu1(f1.z); f1.w = elu1(f1.w);
        f2.x = elu1(f2.x); f2.y = elu1(f2.y); f2.z = elu1(f2.z); f2.w = elu1(f2.w);
        f3.x = elu1(f3.x); f3.y = elu1(f3.y); f3.z = elu1(f3.z); f3.w = elu1(f3.w);
        as0.u = pack8bf(f0, f1);
        as1.u = pack8bf(f2, f3);
    }
    floatx4 AD[4], AM[4];
    #pragma unroll
    for (int j = 0; j < 4; ++j) { AD[j] = (floatx4)(0.f); AM[j] = (floatx4)(0.f); }
    #pragma unroll
    for (int j = 0; j < 4; ++j) {
        FragU bv0, bv1, bm0, bm1;
        bv0.u = *(const uint4*)&VT[(j * 16 + lm) * 72 + quad * 8];
        bv1.u = *(const uint4*)&VT[(j * 16 + lm) * 72 + 32 + quad * 8];
        bm0.u = *(const uint4*)&MT[(j * 16 + lm) * 72 + quad * 8];
        bm1.u = *(const uint4*)&MT[(j * 16 + lm) * 72 + 32 + quad * 8];
        AD[j] = __builtin_amdgcn_mfma_f32_16x16x32_bf16(ap0.b, bv0.b, AD[j], 0, 0, 0);
        AD[j] = __builtin_amdgcn_mfma_f32_16x16x32_bf16(ap1.b, bv1.b, AD[j], 0, 0, 0);
        AM[j] = __builtin_amdgcn_mfma_f32_16x16x32_bf16(as0.b, bm0.b, AM[j], 0, 0, 0);
        AM[j] = __builtin_amdgcn_mfma_f32_16x16x32_bf16(as1.b, bm1.b, AM[j], 0, 0, 0);
    }
    // ---- combine + store attn bf16
    #pragma unroll
    for (int j = 0; j < 4; ++j) {
        const int d = j * 16 + lm;
        const float zd = zr[d];
        #pragma unroll
        for (int r = 0; r < 4; ++r) {
            const int s_g = srow0 + r;
            const float den = rs[s_g] * zd + 1e-6f;
            const float o = gate * (AM[j][r] / den) + omg * AD[j][r];
            ab[base + (size_t)s_g * 64 + d] = f2bf(o);
        }
    }
}

extern "C" void kernel_launch(void* const* d_in, const int* in_sizes, int n_in,
                              void* d_out, int out_size, void* d_ws, size_t ws_size,
                              hipStream_t stream) {
    const float* x    = (const float*)d_in[0];
    const float* Wq   = (const float*)d_in[1];
    const float* bq   = (const float*)d_in[2];
    const float* Wk   = (const float*)d_in[3];
    const float* bk   = (const float*)d_in[4];
    const float* Wv   = (const float*)d_in[5];
    const float* bv   = (const float*)d_in[6];
    const float* Wo   = (const float*)d_in[7];
    const float* bo   = (const float*)d_in[8];
    const float* beta = (const float*)d_in[9];
    float* out = (float*)d_out;

    unsigned char* wsb = (unsigned char*)d_ws;
    unsigned short* xb  = (unsigned short*)(wsb);                       // 32 MB; reused as ab
    unsigned short* wb  = (unsigned short*)(wsb + (32ull << 20));       // 12 MB  [3072][2048]
    unsigned short* wob = (unsigned short*)(wsb + (44ull << 20));       // 2 MB   [1024][1024]
    unsigned short* qb  = (unsigned short*)(wsb + (46ull << 20));       // 16 MB
    unsigned short* kb  = (unsigned short*)(wsb + (62ull << 20));       // 16 MB
    unsigned short* vb  = (unsigned short*)(wsb + (78ull << 20));       // 16 MB
    float* Skv = (float*)(wsb + (94ull << 20));                         // 32 MB
    float* zc  = (float*)(wsb + (126ull << 20));                        // 0.5 MB
    unsigned short* ab = xb;   // attn bf16 (xb dead after gemm_qkv)

    cvt_bf16<<<8192, 256, 0, stream>>>(x, xb, 2097152);
    cvt_w<<<3584, 256, 0, stream>>>(Wq, Wk, Wv, Wo, wb, wob);

    gemm_qkv256<<<dim3(12, 32), 512, 0, stream>>>(xb, wb, bq, bk, bv, qb, kb, vb);
    seg_kv<<<2048, 256, 0, stream>>>(kb, vb, Skv, zc);
    prefix_mem<<<dim3(8, 128), 256, 0, stream>>>(Skv, zc);
    seg_attn<<<2048, 256, 0, stream>>>(qb, kb, vb, Skv, zc, beta, ab);
    gemm_out256<<<dim3(4, 32), 512, 0, stream>>>(ab, wob, bo, out);
}

// Round 6
// 339.626 us; speedup vs baseline: 1.2495x; 1.2336x over previous
//
#include <hip/hip_runtime.h>
#include <hip/hip_bf16.h>
#include <cstddef>

#define EE 1024            // E
#define MTOT 8192          // B*E

using floatx4 = __attribute__((ext_vector_type(4))) float;
using bf16x8  = __attribute__((ext_vector_type(8))) __bf16;

union FragU { uint4 u; bf16x8 b; };

__device__ __forceinline__ float elu1(float x) {
    return x > 0.f ? x + 1.f : __expf(x);
}

__device__ __forceinline__ unsigned int pack2bf(float x, float y) {
    __hip_bfloat162 h = __float22bfloat162_rn(make_float2(x, y));
    union { __hip_bfloat162 h; unsigned int u; } c;
    c.h = h;
    return c.u;
}

__device__ __forceinline__ uint4 pack8bf(const float4 a, const float4 b) {
    uint4 r;
    r.x = pack2bf(a.x, a.y); r.y = pack2bf(a.z, a.w);
    r.z = pack2bf(b.x, b.y); r.w = pack2bf(b.z, b.w);
    return r;
}

__device__ __forceinline__ unsigned short f2bf(float x) {
    union { __hip_bfloat16 h; unsigned short s; } c;
    c.h = __float2bfloat16(x);
    return c.s;
}

__device__ __forceinline__ void unp8(const uint4 p, float4& a, float4& b) {
    a.x = __uint_as_float(p.x << 16); a.y = __uint_as_float(p.x & 0xffff0000u);
    a.z = __uint_as_float(p.y << 16); a.w = __uint_as_float(p.y & 0xffff0000u);
    b.x = __uint_as_float(p.z << 16); b.y = __uint_as_float(p.z & 0xffff0000u);
    b.z = __uint_as_float(p.w << 16); b.w = __uint_as_float(p.w & 0xffff0000u);
}

__device__ __forceinline__ void ld_lds16(const unsigned short* g, unsigned short* l) {
    __builtin_amdgcn_global_load_lds(
        (const __attribute__((address_space(1))) void*)g,
        (__attribute__((address_space(3))) void*)l, 16, 0, 0);
}

// Fused fp32 -> bf16 bulk convert: x | Wq | Wk | Wv | Wo in one launch.
// uint4-chunk regions: x 2097152 | Wq 262144 | Wk 262144 | Wv 262144 | Wo 131072
__global__ __launch_bounds__(256)
void cvt_all(const float* __restrict__ x,
             const float* __restrict__ Wq, const float* __restrict__ Wk,
             const float* __restrict__ Wv, const float* __restrict__ Wo,
             unsigned short* __restrict__ xb,
             unsigned short* __restrict__ wb, unsigned short* __restrict__ wob) {
    const int i = blockIdx.x * 256 + threadIdx.x;
    if (i >= 3014656) return;
    const float* src;
    unsigned short* dst;
    int off;
    if (i < 2097152)      { src = x;  dst = xb;           off = i; }
    else if (i < 2359296) { src = Wq; dst = wb;           off = i - 2097152; }
    else if (i < 2621440) { src = Wk; dst = wb + 2097152; off = i - 2359296; }
    else if (i < 2883584) { src = Wv; dst = wb + 4194304; off = i - 2621440; }
    else                  { src = Wo; dst = wob;          off = i - 2883584; }
    const float4 a = ((const float4*)src)[2 * off];
    const float4 b = ((const float4*)src)[2 * off + 1];
    ((uint4*)dst)[off] = pack8bf(a, b);
}

// ---- m97-style MFMA core: bf16 A[M][K] x B[N][K]^T, 128x128 tile, BK=32,
// global_load_lds width-16 staging, LDS [128][32] ushort (64B rows).
//
// Chunk swizzle (fixes round-0's measured 1.26e7 read conflicts): chunk c of
// row r is stored at chunk c' = (c + (r>>1)) & 3. Read slot within 128B =
// (lm&1)*4 + (lq + (lm>>1))&3 -> 8 distinct per octet, 2-way per 16 lanes
// (free, m136). Staging keeps the LINEAR global_load_lds dest and applies the
// inverse rotation on the global SOURCE chunk (ac), staying inside each 64B
// row segment -> coalescing preserved (same involution both sides).
//   stage:  lane l -> LDS row 32w+(l>>2), chunk l&3; (r>>1)&3 = (l>>3)&3
//           -> source chunk = ((l&3) - ((l>>3)&3)) & 3
//   read:   row = {wm|wn}+i*16+lm -> (r>>1)&3 = (lm>>1)&3 (wm,i*16 drop out)
template<int K>
__device__ __forceinline__ void mfma_core(const unsigned short* __restrict__ A,
                                          const unsigned short* __restrict__ B,
                                          int m0, int n0,
                                          unsigned short* As, unsigned short* Bs,
                                          floatx4 (&acc)[4][4]) {
    const int t = threadIdx.x;
    const int w = t >> 6, l = t & 63;
    const int wm = (w >> 1) * 64, wn = (w & 1) * 64;
    const int lm = l & 15, lq = l >> 4;
    const int ar = l >> 2;
    const int ac = (((l & 3) - ((l >> 3) & 3)) & 3) * 8;   // pre-swizzled source chunk
    const int sw = (lm >> 1) & 3;                          // read-side rotation
    const unsigned short* Ag0 = A + (size_t)(m0 + 32 * w + ar) * K + ac;
    const unsigned short* Ag1 = Ag0 + (size_t)16 * K;
    const unsigned short* Bg0 = B + (size_t)(n0 + 32 * w + ar) * K + ac;
    const unsigned short* Bg1 = Bg0 + (size_t)16 * K;
    unsigned short* Al0 = As + 1024 * w;
    unsigned short* Al1 = As + 1024 * w + 512;
    unsigned short* Bl0 = Bs + 1024 * w;
    unsigned short* Bl1 = Bs + 1024 * w + 512;

    for (int kb = 0; kb < K; kb += 32) {
        __syncthreads();
        ld_lds16(Ag0 + kb, Al0);
        ld_lds16(Ag1 + kb, Al1);
        ld_lds16(Bg0 + kb, Bl0);
        ld_lds16(Bg1 + kb, Bl1);
        __syncthreads();
        FragU af[4], bf[4];
        #pragma unroll
        for (int i = 0; i < 4; ++i)
            af[i].u = *(const uint4*)&As[(wm + i * 16 + lm) * 32 + ((lq + sw) & 3) * 8];
        #pragma unroll
        for (int j = 0; j < 4; ++j)
            bf[j].u = *(const uint4*)&Bs[(wn + j * 16 + lm) * 32 + ((lq + sw) & 3) * 8];
        #pragma unroll
        for (int i = 0; i < 4; ++i)
            #pragma unroll
            for (int j = 0; j < 4; ++j)
                acc[i][j] = __builtin_amdgcn_mfma_f32_16x16x32_bf16(
                    af[i].b, bf[j].b, acc[i][j], 0, 0, 0);
    }
}

// Fused QKV projection: A=xb [8192][2048], B=wb [3072][2048] (Wq|Wk|Wv rows).
__global__ __launch_bounds__(256)
void gemm_qkv(const unsigned short* __restrict__ A, const unsigned short* __restrict__ B,
              const float* __restrict__ bq, const float* __restrict__ bk,
              const float* __restrict__ bv,
              unsigned short* __restrict__ qb, unsigned short* __restrict__ kb,
              unsigned short* __restrict__ vb) {
    __shared__ __align__(16) unsigned short As[128 * 32];
    __shared__ __align__(16) unsigned short Bs[128 * 32];
    const int m0 = blockIdx.y * 128;
    const int n0 = blockIdx.x * 128;
    floatx4 acc[4][4];
    #pragma unroll
    for (int i = 0; i < 4; ++i)
        #pragma unroll
        for (int j = 0; j < 4; ++j)
            acc[i][j] = (floatx4)(0.f);
    mfma_core<2048>(A, B, m0, n0, As, Bs, acc);

    const int t = threadIdx.x;
    const int w = t >> 6, l = t & 63;
    const int wm = (w >> 1) * 64, wn = (w & 1) * 64;
    const int lm = l & 15, lq = l >> 4;
    const int proj = n0 >> 10;
    unsigned short* Cb = proj == 0 ? qb : (proj == 1 ? kb : vb);
    const float* bias  = proj == 0 ? bq : (proj == 1 ? bk : bv);
    const int nd = n0 & 1023;
    #pragma unroll
    for (int j = 0; j < 4; ++j) {
        const int d = nd + wn + j * 16 + lm;
        const float bj = bias[d];
        #pragma unroll
        for (int i = 0; i < 4; ++i) {
            #pragma unroll
            for (int r = 0; r < 4; ++r) {
                const int row = m0 + wm + i * 16 + lq * 4 + r;
                Cb[(size_t)row * 1024 + d] = f2bf(acc[i][j][r] + bj);
            }
        }
    }
}

// Output projection: A=attn bf16 [8192][1024], B=wob [1024][1024]. fp32 out.
__global__ __launch_bounds__(256)
void gemm_out(const unsigned short* __restrict__ A, const unsigned short* __restrict__ B,
              const float* __restrict__ bo, float* __restrict__ C) {
    __shared__ __align__(16) unsigned short As[128 * 32];
    __shared__ __align__(16) unsigned short Bs[128 * 32];
    const int m0 = blockIdx.y * 128;
    const int n0 = blockIdx.x * 128;
    floatx4 acc[4][4];
    #pragma unroll
    for (int i = 0; i < 4; ++i)
        #pragma unroll
        for (int j = 0; j < 4; ++j)
            acc[i][j] = (floatx4)(0.f);
    mfma_core<1024>(A, B, m0, n0, As, Bs, acc);

    const int t = threadIdx.x;
    const int w = t >> 6, l = t & 63;
    const int wm = (w >> 1) * 64, wn = (w & 1) * 64;
    const int lm = l & 15, lq = l >> 4;
    #pragma unroll
    for (int j = 0; j < 4; ++j) {
        const int col = n0 + wn + j * 16 + lm;
        const float bj = bo[col];
        #pragma unroll
        for (int i = 0; i < 4; ++i) {
            #pragma unroll
            for (int r = 0; r < 4; ++r) {
                const int row = m0 + wm + i * 16 + lq * 4 + r;
                C[(size_t)row * EE + col] = acc[i][j][r] + bj;
            }
        }
    }
}

// ---- Stage 1 (MFMA): Sk[d][e] = sum_s sigma_k[s][d]*v[s][e], z[d]=colsum(sigma_k).
__global__ __launch_bounds__(256)
void seg_kv(const unsigned short* __restrict__ k, const unsigned short* __restrict__ v,
            float* __restrict__ Skv, float* __restrict__ zc) {
    __shared__ __align__(16) unsigned short KT[64 * 72];  // sigma_k^T [d][s]
    __shared__ __align__(16) unsigned short VT[64 * 72];  // v^T       [e][s]
    const int t = threadIdx.x;
    const int w = t >> 6, l = t & 63, quad = l >> 4, lm = l & 15;
    const size_t base = (size_t)blockIdx.x * 4096;

    #pragma unroll
    for (int i = 0; i < 2; ++i) {
        const int c  = t + i * 256;            // uint4 chunk
        const int sr = c >> 3, c0 = (c & 7) * 8;
        const uint4 pk = *(const uint4*)(k + base + c * 8);
        const uint4 pv = *(const uint4*)(v + base + c * 8);
        float4 f0, f1;
        unp8(pk, f0, f1);
        KT[(c0 + 0) * 72 + sr] = f2bf(elu1(f0.x));
        KT[(c0 + 1) * 72 + sr] = f2bf(elu1(f0.y));
        KT[(c0 + 2) * 72 + sr] = f2bf(elu1(f0.z));
        KT[(c0 + 3) * 72 + sr] = f2bf(elu1(f0.w));
        KT[(c0 + 4) * 72 + sr] = f2bf(elu1(f1.x));
        KT[(c0 + 5) * 72 + sr] = f2bf(elu1(f1.y));
        KT[(c0 + 6) * 72 + sr] = f2bf(elu1(f1.z));
        KT[(c0 + 7) * 72 + sr] = f2bf(elu1(f1.w));
        const unsigned short* pvs = (const unsigned short*)&pv;
        #pragma unroll
        for (int jj = 0; jj < 8; ++jj) VT[(c0 + jj) * 72 + sr] = pvs[jj];
    }
    __syncthreads();

    if (t < 64) {                                  // z[d] = rowsum of KT row d
        float ssum = 0.f;
        #pragma unroll
        for (int c2 = 0; c2 < 8; ++c2) {
            const uint4 p = *(const uint4*)&KT[t * 72 + c2 * 8];
            float4 a, b;
            unp8(p, a, b);
            ssum += a.x + a.y + a.z + a.w + b.x + b.y + b.z + b.w;
        }
        zc[(size_t)blockIdx.x * 64 + t] = ssum;
    }

    FragU ak0, ak1;
    ak0.u = *(const uint4*)&KT[(16 * w + lm) * 72 + quad * 8];
    ak1.u = *(const uint4*)&KT[(16 * w + lm) * 72 + 32 + quad * 8];
    floatx4 C4[4];
    #pragma unroll
    for (int j = 0; j < 4; ++j) C4[j] = (floatx4)(0.f);
    #pragma unroll
    for (int j = 0; j < 4; ++j) {
        FragU b0, b1;
        b0.u = *(const uint4*)&VT[(j * 16 + lm) * 72 + quad * 8];
        b1.u = *(const uint4*)&VT[(j * 16 + lm) * 72 + 32 + quad * 8];
        C4[j] = __builtin_amdgcn_mfma_f32_16x16x32_bf16(ak0.b, b0.b, C4[j], 0, 0, 0);
        C4[j] = __builtin_amdgcn_mfma_f32_16x16x32_bf16(ak1.b, b1.b, C4[j], 0, 0, 0);
    }
    const int d0 = 16 * w + quad * 4;
    #pragma unroll
    for (int j = 0; j < 4; ++j)
        #pragma unroll
        for (int r = 0; r < 4; ++r)
            Skv[base + (size_t)(d0 + r) * 64 + j * 16 + lm] = C4[j][r];
}

// ---- Stage 2: exclusive prefix over 16 segments per (b,h) chain.
__global__ __launch_bounds__(256)
void prefix_mem(float* __restrict__ Skv, float* __restrict__ zc) {
    const int t  = threadIdx.x;
    const int bh = blockIdx.y;
    float* p0 = Skv + (size_t)bh * 16 * 4096 + blockIdx.x * 512 + t * 2;
    float2 acc = make_float2(0.f, 0.f);
    #pragma unroll
    for (int n = 0; n < 16; ++n) {
        float2* p = (float2*)(p0 + (size_t)n * 4096);
        const float2 tmp = *p;
        *p = acc;
        acc.x += tmp.x; acc.y += tmp.y;
    }
    if (blockIdx.x == 0 && t < 64) {
        float* zp0 = zc + (size_t)bh * 16 * 64 + t;
        float za = 0.f;
        #pragma unroll
        for (int n = 0; n < 16; ++n) {
            float* zp = zp0 + n * 64;
            const float tmp = *zp;
            *zp = za;
            za += tmp;
        }
    }
}

// ---- Stage 3 (MFMA): per-segment attention.
__global__ __launch_bounds__(256)
void seg_attn(const unsigned short* __restrict__ q, const unsigned short* __restrict__ k,
              const unsigned short* __restrict__ v, const float* __restrict__ memp,
              const float* __restrict__ zp, const float* __restrict__ beta,
              unsigned short* __restrict__ ab) {
    __shared__ __align__(16) unsigned short Pb[64 * 72];  // P bf16 [s][t]
    __shared__ __align__(16) unsigned short VT[64 * 72];  // v^T    [e][s]
    __shared__ __align__(16) unsigned short MT[64 * 72];  // mem^T  [e][d]
    __shared__ float rs[64];
    __shared__ float zr[64];
    const int t = threadIdx.x;
    const int w = t >> 6, l = t & 63, quad = l >> 4, lm = l & 15;
    const int seg = blockIdx.x;
    const int h   = (seg >> 4) & 15;
    const float gate = 1.f / (1.f + __expf(-10.f * beta[h]));
    const float omg  = 1.f - gate;
    const size_t base = (size_t)seg * 4096;

    // stage v^T
    #pragma unroll
    for (int i = 0; i < 2; ++i) {
        const int c  = t + i * 256;
        const int sr = c >> 3, c0 = (c & 7) * 8;
        const uint4 pv = *(const uint4*)(v + base + c * 8);
        const unsigned short* pvs = (const unsigned short*)&pv;
        #pragma unroll
        for (int jj = 0; jj < 8; ++jj) VT[(c0 + jj) * 72 + sr] = pvs[jj];
    }
    // stage mem^T (fp32 -> bf16)
    #pragma unroll
    for (int i = 0; i < 4; ++i) {
        const int c = t + i * 256;               // float4 chunk
        const int d = c >> 4, e0 = (c & 15) * 4;
        const float4 m4 = *(const float4*)(memp + base + c * 4);
        MT[(e0 + 0) * 72 + d] = f2bf(m4.x);
        MT[(e0 + 1) * 72 + d] = f2bf(m4.y);
        MT[(e0 + 2) * 72 + d] = f2bf(m4.z);
        MT[(e0 + 3) * 72 + d] = f2bf(m4.w);
    }
    // rs[s] = rowsum(sigma_q): quarter-row per thread + shfl reduce
    {
        const int s = t >> 2, dq = (t & 3) * 16;
        const uint4 a0 = *(const uint4*)(q + base + s * 64 + dq);
        const uint4 a1 = *(const uint4*)(q + base + s * 64 + dq + 8);
        float4 f0, f1, f2, f3;
        unp8(a0, f0, f1); unp8(a1, f2, f3);
        float p = elu1(f0.x) + elu1(f0.y) + elu1(f0.z) + elu1(f0.w)
                + elu1(f1.x) + elu1(f1.y) + elu1(f1.z) + elu1(f1.w)
                + elu1(f2.x) + elu1(f2.y) + elu1(f2.z) + elu1(f2.w)
                + elu1(f3.x) + elu1(f3.y) + elu1(f3.z) + elu1(f3.w);
        p += __shfl_xor(p, 1, 64);
        p += __shfl_xor(p, 2, 64);
        if ((t & 3) == 0) rs[s] = p;
    }
    if (t < 64) zr[t] = zp[(size_t)seg * 64 + t];
    __syncthreads();

    // ---- scores: wave w computes rows [16w,16w+16) x all 64 cols
    const unsigned short* qrow = q + base + (size_t)(16 * w + lm) * 64;
    FragU aq0, aq1;
    aq0.u = *(const uint4*)(qrow + quad * 8);
    aq1.u = *(const uint4*)(qrow + 32 + quad * 8);
    floatx4 S[4];
    #pragma unroll
    for (int j = 0; j < 4; ++j) S[j] = (floatx4)(0.f);
    #pragma unroll
    for (int j = 0; j < 4; ++j) {
        const unsigned short* krow = k + base + (size_t)(j * 16 + lm) * 64;
        FragU b0, b1;
        b0.u = *(const uint4*)(krow + quad * 8);
        b1.u = *(const uint4*)(krow + 32 + quad * 8);
        S[j] = __builtin_amdgcn_mfma_f32_16x16x32_bf16(aq0.b, b0.b, S[j], 0, 0, 0);
        S[j] = __builtin_amdgcn_mfma_f32_16x16x32_bf16(aq1.b, b1.b, S[j], 0, 0, 0);
    }
    // ---- causal softmax in C-layout registers; write P bf16 to LDS
    const int srow0 = 16 * w + quad * 4;
    #pragma unroll
    for (int r = 0; r < 4; ++r) {
        const int s_g = srow0 + r;
        float m = -3.0e38f;
        #pragma unroll
        for (int j = 0; j < 4; ++j) {
            const int t_g = j * 16 + lm;
            const float val = (t_g <= s_g) ? S[j][r] * 0.125f : -3.0e38f;
            S[j][r] = val;
            m = fmaxf(m, val);
        }
        m = fmaxf(m, __shfl_xor(m, 1, 64));
        m = fmaxf(m, __shfl_xor(m, 2, 64));
        m = fmaxf(m, __shfl_xor(m, 4, 64));
        m = fmaxf(m, __shfl_xor(m, 8, 64));
        float ss = 0.f;
        #pragma unroll
        for (int j = 0; j < 4; ++j) {
            const int t_g = j * 16 + lm;
            const float e = (t_g <= s_g) ? __expf(S[j][r] - m) : 0.f;
            S[j][r] = e;
            ss += e;
        }
        ss += __shfl_xor(ss, 1, 64);
        ss += __shfl_xor(ss, 2, 64);
        ss += __shfl_xor(ss, 4, 64);
        ss += __shfl_xor(ss, 8, 64);
        const float inv = 1.f / ss;
        #pragma unroll
        for (int j = 0; j < 4; ++j)
            Pb[s_g * 72 + j * 16 + lm] = f2bf(S[j][r] * inv);
    }
    __syncthreads();

    // ---- A_dot = P@V and A_mem = sigma_q@mem (both C-layout accumulators)
    FragU ap0, ap1, as0, as1;
    ap0.u = *(const uint4*)&Pb[(16 * w + lm) * 72 + quad * 8];
    ap1.u = *(const uint4*)&Pb[(16 * w + lm) * 72 + 32 + quad * 8];
    {
        float4 f0, f1, f2, f3;
        unp8(aq0.u, f0, f1);
        unp8(aq1.u, f2, f3);
        f0.x = elu1(f0.x); f0.y = elu1(f0.y); f0.z = elu1(f0.z); f0.w = elu1(f0.w);
        f1.x = elu1(f1.x); f1.y = elu1(f1.y); f1.z = elu1(f1.z); f1.w = elu1(f1.w);
        f2.x = elu1(f2.x); f2.y = elu1(f2.y); f2.z = elu1(f2.z); f2.w = elu1(f2.w);
        f3.x = elu1(f3.x); f3.y = elu1(f3.y); f3.z = elu1(f3.z); f3.w = elu1(f3.w);
        as0.u = pack8bf(f0, f1);
        as1.u = pack8bf(f2, f3);
    }
    floatx4 AD[4], AM[4];
    #pragma unroll
    for (int j = 0; j < 4; ++j) { AD[j] = (floatx4)(0.f); AM[j] = (floatx4)(0.f); }
    #pragma unroll
    for (int j = 0; j < 4; ++j) {
        FragU bv0, bv1, bm0, bm1;
        bv0.u = *(const uint4*)&VT[(j * 16 + lm) * 72 + quad * 8];
        bv1.u = *(const uint4*)&VT[(j * 16 + lm) * 72 + 32 + quad * 8];
        bm0.u = *(const uint4*)&MT[(j * 16 + lm) * 72 + quad * 8];
        bm1.u = *(const uint4*)&MT[(j * 16 + lm) * 72 + 32 + quad * 8];
        AD[j] = __builtin_amdgcn_mfma_f32_16x16x32_bf16(ap0.b, bv0.b, AD[j], 0, 0, 0);
        AD[j] = __builtin_amdgcn_mfma_f32_16x16x32_bf16(ap1.b, bv1.b, AD[j], 0, 0, 0);
        AM[j] = __builtin_amdgcn_mfma_f32_16x16x32_bf16(as0.b, bm0.b, AM[j], 0, 0, 0);
        AM[j] = __builtin_amdgcn_mfma_f32_16x16x32_bf16(as1.b, bm1.b, AM[j], 0, 0, 0);
    }
    // ---- combine + store attn bf16
    #pragma unroll
    for (int j = 0; j < 4; ++j) {
        const int d = j * 16 + lm;
        const float zd = zr[d];
        #pragma unroll
        for (int r = 0; r < 4; ++r) {
            const int s_g = srow0 + r;
            const float den = rs[s_g] * zd + 1e-6f;
            const float o = gate * (AM[j][r] / den) + omg * AD[j][r];
            ab[base + (size_t)s_g * 64 + d] = f2bf(o);
        }
    }
}

extern "C" void kernel_launch(void* const* d_in, const int* in_sizes, int n_in,
                              void* d_out, int out_size, void* d_ws, size_t ws_size,
                              hipStream_t stream) {
    const float* x    = (const float*)d_in[0];
    const float* Wq   = (const float*)d_in[1];
    const float* bq   = (const float*)d_in[2];
    const float* Wk   = (const float*)d_in[3];
    const float* bk   = (const float*)d_in[4];
    const float* Wv   = (const float*)d_in[5];
    const float* bv   = (const float*)d_in[6];
    const float* Wo   = (const float*)d_in[7];
    const float* bo   = (const float*)d_in[8];
    const float* beta = (const float*)d_in[9];
    float* out = (float*)d_out;

    unsigned char* wsb = (unsigned char*)d_ws;
    unsigned short* xb  = (unsigned short*)(wsb);                       // 32 MB; reused as ab
    unsigned short* wb  = (unsigned short*)(wsb + (32ull << 20));       // 12 MB  [3072][2048]
    unsigned short* wob = (unsigned short*)(wsb + (44ull << 20));       // 2 MB   [1024][1024]
    unsigned short* qb  = (unsigned short*)(wsb + (46ull << 20));       // 16 MB
    unsigned short* kb  = (unsigned short*)(wsb + (62ull << 20));       // 16 MB
    unsigned short* vb  = (unsigned short*)(wsb + (78ull << 20));       // 16 MB
    float* Skv = (float*)(wsb + (94ull << 20));                         // 32 MB
    float* zc  = (float*)(wsb + (126ull << 20));                        // 0.5 MB
    unsigned short* ab = xb;   // attn bf16 (xb dead after gemm_qkv)

    cvt_all<<<11776, 256, 0, stream>>>(x, Wq, Wk, Wv, Wo, xb, wb, wob);

    gemm_qkv<<<dim3(24, 64), 256, 0, stream>>>(xb, wb, bq, bk, bv, qb, kb, vb);
    seg_kv<<<2048, 256, 0, stream>>>(kb, vb, Skv, zc);
    prefix_mem<<<dim3(8, 128), 256, 0, stream>>>(Skv, zc);
    seg_attn<<<2048, 256, 0, stream>>>(qb, kb, vb, Skv, zc, beta, ab);
    gemm_out<<<dim3(8, 64), 256, 0, stream>>>(ab, wob, bo, out);
}

// Round 7
// 328.520 us; speedup vs baseline: 1.2918x; 1.0338x over previous
//
#include <hip/hip_runtime.h>
#include <hip/hip_bf16.h>
#include <cstddef>

#define EE 1024            // E
#define MTOT 8192          // B*E

using floatx4 = __attribute__((ext_vector_type(4))) float;
using bf16x8  = __attribute__((ext_vector_type(8))) __bf16;

union FragU { uint4 u; bf16x8 b; };

__device__ __forceinline__ float elu1(float x) {
    return x > 0.f ? x + 1.f : __expf(x);
}

__device__ __forceinline__ unsigned int pack2bf(float x, float y) {
    __hip_bfloat162 h = __float22bfloat162_rn(make_float2(x, y));
    union { __hip_bfloat162 h; unsigned int u; } c;
    c.h = h;
    return c.u;
}

__device__ __forceinline__ uint4 pack8bf(const float4 a, const float4 b) {
    uint4 r;
    r.x = pack2bf(a.x, a.y); r.y = pack2bf(a.z, a.w);
    r.z = pack2bf(b.x, b.y); r.w = pack2bf(b.z, b.w);
    return r;
}

__device__ __forceinline__ unsigned short f2bf(float x) {
    union { __hip_bfloat16 h; unsigned short s; } c;
    c.h = __float2bfloat16(x);
    return c.s;
}

__device__ __forceinline__ void unp8(const uint4 p, float4& a, float4& b) {
    a.x = __uint_as_float(p.x << 16); a.y = __uint_as_float(p.x & 0xffff0000u);
    a.z = __uint_as_float(p.y << 16); a.w = __uint_as_float(p.y & 0xffff0000u);
    b.x = __uint_as_float(p.z << 16); b.y = __uint_as_float(p.z & 0xffff0000u);
    b.z = __uint_as_float(p.w << 16); b.w = __uint_as_float(p.w & 0xffff0000u);
}

__device__ __forceinline__ void ld_lds16(const unsigned short* g, unsigned short* l) {
    __builtin_amdgcn_global_load_lds(
        (const __attribute__((address_space(1))) void*)g,
        (__attribute__((address_space(3))) void*)l, 16, 0, 0);
}

// Fused fp32 -> bf16 bulk convert: x | Wq | Wk | Wv | Wo in one launch.
// uint4-chunk regions: x 2097152 | Wq 262144 | Wk 262144 | Wv 262144 | Wo 131072
__global__ __launch_bounds__(256)
void cvt_all(const float* __restrict__ x,
             const float* __restrict__ Wq, const float* __restrict__ Wk,
             const float* __restrict__ Wv, const float* __restrict__ Wo,
             unsigned short* __restrict__ xb,
             unsigned short* __restrict__ wb, unsigned short* __restrict__ wob) {
    const int i = blockIdx.x * 256 + threadIdx.x;
    if (i >= 3014656) return;
    const float* src;
    unsigned short* dst;
    int off;
    if (i < 2097152)      { src = x;  dst = xb;           off = i; }
    else if (i < 2359296) { src = Wq; dst = wb;           off = i - 2097152; }
    else if (i < 2621440) { src = Wk; dst = wb + 2097152; off = i - 2359296; }
    else if (i < 2883584) { src = Wv; dst = wb + 4194304; off = i - 2621440; }
    else                  { src = Wo; dst = wob;          off = i - 2883584; }
    const float4 a = ((const float4*)src)[2 * off];
    const float4 b = ((const float4*)src)[2 * off + 1];
    ((uint4*)dst)[off] = pack8bf(a, b);
}

// ---- m97-style MFMA core, BK=64: bf16 A[M][K] x B[N][K]^T, 128x128 tile,
// global_load_lds width-16 staging, LDS [128][64] ushort (128B rows), 32 KiB.
//
// BK=32->64 rationale: each K-step's 2nd __syncthreads forces a vmcnt(0)
// drain (structural m97 stall), exposing full L2/HBM latency per step.
// BK=64 halves the exposures and doubles MFMA per exposure (32/step).
//
// Chunk swizzle for 128B rows (8 x 16B chunks): chunk c of row r stored at
// (c + r) & 7.  Read (row = wm|wn + i*16 + lm, all offsets =0 mod 8 so
// r&7 = lm&7): frag kh chunk = lq + 4*kh -> slot ((lq + lm) & 7) ^ (4*kh).
// Octet (lm 0..7 / 8..15, lq fixed): 8 distinct slots -> conflict-free; 16-lane
// group 2-way = free (m136; verified 0 conflicts in round 6 with the 64B
// variant of this scheme).
// Staging keeps LINEAR wave-uniform global_load_lds dest; inverse rotation on
// the global SOURCE chunk: lane l -> row base+ (l>>3), dest chunk l&7, source
// chunk ((l&7) - (l>>3)) & 7  (rotation within each 128B row -> coalescing
// preserved; same involution both sides, rule #21).
template<int K>
__device__ __forceinline__ void mfma_core(const unsigned short* __restrict__ A,
                                          const unsigned short* __restrict__ B,
                                          int m0, int n0,
                                          unsigned short* As, unsigned short* Bs,
                                          floatx4 (&acc)[4][4]) {
    const int t = threadIdx.x;
    const int w = t >> 6, l = t & 63;
    const int wm = (w >> 1) * 64, wn = (w & 1) * 64;
    const int lm = l & 15, lq = l >> 4;
    const int lr = l >> 3;                       // row within 8-row stage group
    const int sc = ((l & 7) - lr) & 7;           // pre-swizzled source chunk
    const int c0 = (lq + lm) & 7;                // read-side base slot

    const unsigned short* Ag = A + (size_t)(m0 + 32 * w + lr) * K + sc * 8;
    const unsigned short* Bg = B + (size_t)(n0 + 32 * w + lr) * K + sc * 8;
    unsigned short* Al = As + (32 * w) * 64;
    unsigned short* Bl = Bs + (32 * w) * 64;

    for (int kb = 0; kb < K; kb += 64) {
        __syncthreads();
        #pragma unroll
        for (int p = 0; p < 4; ++p) {
            ld_lds16(Ag + (size_t)(8 * p) * K + kb, Al + (8 * p) * 64);
            ld_lds16(Bg + (size_t)(8 * p) * K + kb, Bl + (8 * p) * 64);
        }
        __syncthreads();
        FragU af[4][2], bf[4][2];
        #pragma unroll
        for (int i = 0; i < 4; ++i) {
            const int row = (wm + i * 16 + lm) * 64;
            af[i][0].u = *(const uint4*)&As[row + c0 * 8];
            af[i][1].u = *(const uint4*)&As[row + (c0 ^ 4) * 8];
        }
        #pragma unroll
        for (int j = 0; j < 4; ++j) {
            const int row = (wn + j * 16 + lm) * 64;
            bf[j][0].u = *(const uint4*)&Bs[row + c0 * 8];
            bf[j][1].u = *(const uint4*)&Bs[row + (c0 ^ 4) * 8];
        }
        #pragma unroll
        for (int i = 0; i < 4; ++i)
            #pragma unroll
            for (int j = 0; j < 4; ++j) {
                acc[i][j] = __builtin_amdgcn_mfma_f32_16x16x32_bf16(
                    af[i][0].b, bf[j][0].b, acc[i][j], 0, 0, 0);
                acc[i][j] = __builtin_amdgcn_mfma_f32_16x16x32_bf16(
                    af[i][1].b, bf[j][1].b, acc[i][j], 0, 0, 0);
            }
    }
}

// Fused QKV projection: A=xb [8192][2048], B=wb [3072][2048] (Wq|Wk|Wv rows).
__global__ __launch_bounds__(256)
void gemm_qkv(const unsigned short* __restrict__ A, const unsigned short* __restrict__ B,
              const float* __restrict__ bq, const float* __restrict__ bk,
              const float* __restrict__ bv,
              unsigned short* __restrict__ qb, unsigned short* __restrict__ kb,
              unsigned short* __restrict__ vb) {
    __shared__ __align__(16) unsigned short As[128 * 64];
    __shared__ __align__(16) unsigned short Bs[128 * 64];
    const int m0 = blockIdx.y * 128;
    const int n0 = blockIdx.x * 128;
    floatx4 acc[4][4];
    #pragma unroll
    for (int i = 0; i < 4; ++i)
        #pragma unroll
        for (int j = 0; j < 4; ++j)
            acc[i][j] = (floatx4)(0.f);
    mfma_core<2048>(A, B, m0, n0, As, Bs, acc);

    const int t = threadIdx.x;
    const int w = t >> 6, l = t & 63;
    const int wm = (w >> 1) * 64, wn = (w & 1) * 64;
    const int lm = l & 15, lq = l >> 4;
    const int proj = n0 >> 10;
    unsigned short* Cb = proj == 0 ? qb : (proj == 1 ? kb : vb);
    const float* bias  = proj == 0 ? bq : (proj == 1 ? bk : bv);
    const int nd = n0 & 1023;
    #pragma unroll
    for (int j = 0; j < 4; ++j) {
        const int d = nd + wn + j * 16 + lm;
        const float bj = bias[d];
        #pragma unroll
        for (int i = 0; i < 4; ++i) {
            #pragma unroll
            for (int r = 0; r < 4; ++r) {
                const int row = m0 + wm + i * 16 + lq * 4 + r;
                Cb[(size_t)row * 1024 + d] = f2bf(acc[i][j][r] + bj);
            }
        }
    }
}

// Output projection: A=attn bf16 [8192][1024], B=wob [1024][1024]. fp32 out.
__global__ __launch_bounds__(256)
void gemm_out(const unsigned short* __restrict__ A, const unsigned short* __restrict__ B,
              const float* __restrict__ bo, float* __restrict__ C) {
    __shared__ __align__(16) unsigned short As[128 * 64];
    __shared__ __align__(16) unsigned short Bs[128 * 64];
    const int m0 = blockIdx.y * 128;
    const int n0 = blockIdx.x * 128;
    floatx4 acc[4][4];
    #pragma unroll
    for (int i = 0; i < 4; ++i)
        #pragma unroll
        for (int j = 0; j < 4; ++j)
            acc[i][j] = (floatx4)(0.f);
    mfma_core<1024>(A, B, m0, n0, As, Bs, acc);

    const int t = threadIdx.x;
    const int w = t >> 6, l = t & 63;
    const int wm = (w >> 1) * 64, wn = (w & 1) * 64;
    const int lm = l & 15, lq = l >> 4;
    #pragma unroll
    for (int j = 0; j < 4; ++j) {
        const int col = n0 + wn + j * 16 + lm;
        const float bj = bo[col];
        #pragma unroll
        for (int i = 0; i < 4; ++i) {
            #pragma unroll
            for (int r = 0; r < 4; ++r) {
                const int row = m0 + wm + i * 16 + lq * 4 + r;
                C[(size_t)row * EE + col] = acc[i][j][r] + bj;
            }
        }
    }
}

// ---- Stage 1 (MFMA): Sk[d][e] = sum_s sigma_k[s][d]*v[s][e], z[d]=colsum(sigma_k).
__global__ __launch_bounds__(256)
void seg_kv(const unsigned short* __restrict__ k, const unsigned short* __restrict__ v,
            float* __restrict__ Skv, float* __restrict__ zc) {
    __shared__ __align__(16) unsigned short KT[64 * 72];  // sigma_k^T [d][s]
    __shared__ __align__(16) unsigned short VT[64 * 72];  // v^T       [e][s]
    const int t = threadIdx.x;
    const int w = t >> 6, l = t & 63, quad = l >> 4, lm = l & 15;
    const size_t base = (size_t)blockIdx.x * 4096;

    #pragma unroll
    for (int i = 0; i < 2; ++i) {
        const int c  = t + i * 256;            // uint4 chunk
        const int sr = c >> 3, c0 = (c & 7) * 8;
        const uint4 pk = *(const uint4*)(k + base + c * 8);
        const uint4 pv = *(const uint4*)(v + base + c * 8);
        float4 f0, f1;
        unp8(pk, f0, f1);
        KT[(c0 + 0) * 72 + sr] = f2bf(elu1(f0.x));
        KT[(c0 + 1) * 72 + sr] = f2bf(elu1(f0.y));
        KT[(c0 + 2) * 72 + sr] = f2bf(elu1(f0.z));
        KT[(c0 + 3) * 72 + sr] = f2bf(elu1(f0.w));
        KT[(c0 + 4) * 72 + sr] = f2bf(elu1(f1.x));
        KT[(c0 + 5) * 72 + sr] = f2bf(elu1(f1.y));
        KT[(c0 + 6) * 72 + sr] = f2bf(elu1(f1.z));
        KT[(c0 + 7) * 72 + sr] = f2bf(elu1(f1.w));
        const unsigned short* pvs = (const unsigned short*)&pv;
        #pragma unroll
        for (int jj = 0; jj < 8; ++jj) VT[(c0 + jj) * 72 + sr] = pvs[jj];
    }
    __syncthreads();

    if (t < 64) {                                  // z[d] = rowsum of KT row d
        float ssum = 0.f;
        #pragma unroll
        for (int c2 = 0; c2 < 8; ++c2) {
            const uint4 p = *(const uint4*)&KT[t * 72 + c2 * 8];
            float4 a, b;
            unp8(p, a, b);
            ssum += a.x + a.y + a.z + a.w + b.x + b.y + b.z + b.w;
        }
        zc[(size_t)blockIdx.x * 64 + t] = ssum;
    }

    FragU ak0, ak1;
    ak0.u = *(const uint4*)&KT[(16 * w + lm) * 72 + quad * 8];
    ak1.u = *(const uint4*)&KT[(16 * w + lm) * 72 + 32 + quad * 8];
    floatx4 C4[4];
    #pragma unroll
    for (int j = 0; j < 4; ++j) C4[j] = (floatx4)(0.f);
    #pragma unroll
    for (int j = 0; j < 4; ++j) {
        FragU b0, b1;
        b0.u = *(const uint4*)&VT[(j * 16 + lm) * 72 + quad * 8];
        b1.u = *(const uint4*)&VT[(j * 16 + lm) * 72 + 32 + quad * 8];
        C4[j] = __builtin_amdgcn_mfma_f32_16x16x32_bf16(ak0.b, b0.b, C4[j], 0, 0, 0);
        C4[j] = __builtin_amdgcn_mfma_f32_16x16x32_bf16(ak1.b, b1.b, C4[j], 0, 0, 0);
    }
    const int d0 = 16 * w + quad * 4;
    #pragma unroll
    for (int j = 0; j < 4; ++j)
        #pragma unroll
        for (int r = 0; r < 4; ++r)
            Skv[base + (size_t)(d0 + r) * 64 + j * 16 + lm] = C4[j][r];
}

// ---- Stage 2: exclusive prefix over 16 segments per (b,h) chain.
__global__ __launch_bounds__(256)
void prefix_mem(float* __restrict__ Skv, float* __restrict__ zc) {
    const int t  = threadIdx.x;
    const int bh = blockIdx.y;
    float* p0 = Skv + (size_t)bh * 16 * 4096 + blockIdx.x * 512 + t * 2;
    float2 acc = make_float2(0.f, 0.f);
    #pragma unroll
    for (int n = 0; n < 16; ++n) {
        float2* p = (float2*)(p0 + (size_t)n * 4096);
        const float2 tmp = *p;
        *p = acc;
        acc.x += tmp.x; acc.y += tmp.y;
    }
    if (blockIdx.x == 0 && t < 64) {
        float* zp0 = zc + (size_t)bh * 16 * 64 + t;
        float za = 0.f;
        #pragma unroll
        for (int n = 0; n < 16; ++n) {
            float* zp = zp0 + n * 64;
            const float tmp = *zp;
            *zp = za;
            za += tmp;
        }
    }
}

// ---- Stage 3 (MFMA): per-segment attention.
__global__ __launch_bounds__(256)
void seg_attn(const unsigned short* __restrict__ q, const unsigned short* __restrict__ k,
              const unsigned short* __restrict__ v, const float* __restrict__ memp,
              const float* __restrict__ zp, const float* __restrict__ beta,
              unsigned short* __restrict__ ab) {
    __shared__ __align__(16) unsigned short Pb[64 * 72];  // P bf16 [s][t]
    __shared__ __align__(16) unsigned short VT[64 * 72];  // v^T    [e][s]
    __shared__ __align__(16) unsigned short MT[64 * 72];  // mem^T  [e][d]
    __shared__ float rs[64];
    __shared__ float zr[64];
    const int t = threadIdx.x;
    const int w = t >> 6, l = t & 63, quad = l >> 4, lm = l & 15;
    const int seg = blockIdx.x;
    const int h   = (seg >> 4) & 15;
    const float gate = 1.f / (1.f + __expf(-10.f * beta[h]));
    const float omg  = 1.f - gate;
    const size_t base = (size_t)seg * 4096;

    // stage v^T
    #pragma unroll
    for (int i = 0; i < 2; ++i) {
        const int c  = t + i * 256;
        const int sr = c >> 3, c0 = (c & 7) * 8;
        const uint4 pv = *(const uint4*)(v + base + c * 8);
        const unsigned short* pvs = (const unsigned short*)&pv;
        #pragma unroll
        for (int jj = 0; jj < 8; ++jj) VT[(c0 + jj) * 72 + sr] = pvs[jj];
    }
    // stage mem^T (fp32 -> bf16)
    #pragma unroll
    for (int i = 0; i < 4; ++i) {
        const int c = t + i * 256;               // float4 chunk
        const int d = c >> 4, e0 = (c & 15) * 4;
        const float4 m4 = *(const float4*)(memp + base + c * 4);
        MT[(e0 + 0) * 72 + d] = f2bf(m4.x);
        MT[(e0 + 1) * 72 + d] = f2bf(m4.y);
        MT[(e0 + 2) * 72 + d] = f2bf(m4.z);
        MT[(e0 + 3) * 72 + d] = f2bf(m4.w);
    }
    // rs[s] = rowsum(sigma_q): quarter-row per thread + shfl reduce
    {
        const int s = t >> 2, dq = (t & 3) * 16;
        const uint4 a0 = *(const uint4*)(q + base + s * 64 + dq);
        const uint4 a1 = *(const uint4*)(q + base + s * 64 + dq + 8);
        float4 f0, f1, f2, f3;
        unp8(a0, f0, f1); unp8(a1, f2, f3);
        float p = elu1(f0.x) + elu1(f0.y) + elu1(f0.z) + elu1(f0.w)
                + elu1(f1.x) + elu1(f1.y) + elu1(f1.z) + elu1(f1.w)
                + elu1(f2.x) + elu1(f2.y) + elu1(f2.z) + elu1(f2.w)
                + elu1(f3.x) + elu1(f3.y) + elu1(f3.z) + elu1(f3.w);
        p += __shfl_xor(p, 1, 64);
        p += __shfl_xor(p, 2, 64);
        if ((t & 3) == 0) rs[s] = p;
    }
    if (t < 64) zr[t] = zp[(size_t)seg * 64 + t];
    __syncthreads();

    // ---- scores: wave w computes rows [16w,16w+16) x all 64 cols
    const unsigned short* qrow = q + base + (size_t)(16 * w + lm) * 64;
    FragU aq0, aq1;
    aq0.u = *(const uint4*)(qrow + quad * 8);
    aq1.u = *(const uint4*)(qrow + 32 + quad * 8);
    floatx4 S[4];
    #pragma unroll
    for (int j = 0; j < 4; ++j) S[j] = (floatx4)(0.f);
    #pragma unroll
    for (int j = 0; j < 4; ++j) {
        const unsigned short* krow = k + base + (size_t)(j * 16 + lm) * 64;
        FragU b0, b1;
        b0.u = *(const uint4*)(krow + quad * 8);
        b1.u = *(const uint4*)(krow + 32 + quad * 8);
        S[j] = __builtin_amdgcn_mfma_f32_16x16x32_bf16(aq0.b, b0.b, S[j], 0, 0, 0);
        S[j] = __builtin_amdgcn_mfma_f32_16x16x32_bf16(aq1.b, b1.b, S[j], 0, 0, 0);
    }
    // ---- causal softmax in C-layout registers; write P bf16 to LDS
    const int srow0 = 16 * w + quad * 4;
    #pragma unroll
    for (int r = 0; r < 4; ++r) {
        const int s_g = srow0 + r;
        float m = -3.0e38f;
        #pragma unroll
        for (int j = 0; j < 4; ++j) {
            const int t_g = j * 16 + lm;
            const float val = (t_g <= s_g) ? S[j][r] * 0.125f : -3.0e38f;
            S[j][r] = val;
            m = fmaxf(m, val);
        }
        m = fmaxf(m, __shfl_xor(m, 1, 64));
        m = fmaxf(m, __shfl_xor(m, 2, 64));
        m = fmaxf(m, __shfl_xor(m, 4, 64));
        m = fmaxf(m, __shfl_xor(m, 8, 64));
        float ss = 0.f;
        #pragma unroll
        for (int j = 0; j < 4; ++j) {
            const int t_g = j * 16 + lm;
            const float e = (t_g <= s_g) ? __expf(S[j][r] - m) : 0.f;
            S[j][r] = e;
            ss += e;
        }
        ss += __shfl_xor(ss, 1, 64);
        ss += __shfl_xor(ss, 2, 64);
        ss += __shfl_xor(ss, 4, 64);
        ss += __shfl_xor(ss, 8, 64);
        const float inv = 1.f / ss;
        #pragma unroll
        for (int j = 0; j < 4; ++j)
            Pb[s_g * 72 + j * 16 + lm] = f2bf(S[j][r] * inv);
    }
    __syncthreads();

    // ---- A_dot = P@V and A_mem = sigma_q@mem (both C-layout accumulators)
    FragU ap0, ap1, as0, as1;
    ap0.u = *(const uint4*)&Pb[(16 * w + lm) * 72 + quad * 8];
    ap1.u = *(const uint4*)&Pb[(16 * w + lm) * 72 + 32 + quad * 8];
    {
        float4 f0, f1, f2, f3;
        unp8(aq0.u, f0, f1);
        unp8(aq1.u, f2, f3);
        f0.x = elu1(f0.x); f0.y = elu1(f0.y); f0.z = elu1(f0.z); f0.w = elu1(f0.w);
        f1.x = elu1(f1.x); f1.y = elu1(f1.y); f1.z = elu1(f1.z); f1.w = elu1(f1.w);
        f2.x = elu1(f2.x); f2.y = elu1(f2.y); f2.z = elu1(f2.z); f2.w = elu1(f2.w);
        f3.x = elu1(f3.x); f3.y = elu1(f3.y); f3.z = elu1(f3.z); f3.w = elu1(f3.w);
        as0.u = pack8bf(f0, f1);
        as1.u = pack8bf(f2, f3);
    }
    floatx4 AD[4], AM[4];
    #pragma unroll
    for (int j = 0; j < 4; ++j) { AD[j] = (floatx4)(0.f); AM[j] = (floatx4)(0.f); }
    #pragma unroll
    for (int j = 0; j < 4; ++j) {
        FragU bv0, bv1, bm0, bm1;
        bv0.u = *(const uint4*)&VT[(j * 16 + lm) * 72 + quad * 8];
        bv1.u = *(const uint4*)&VT[(j * 16 + lm) * 72 + 32 + quad * 8];
        bm0.u = *(const uint4*)&MT[(j * 16 + lm) * 72 + quad * 8];
        bm1.u = *(const uint4*)&MT[(j * 16 + lm) * 72 + 32 + quad * 8];
        AD[j] = __builtin_amdgcn_mfma_f32_16x16x32_bf16(ap0.b, bv0.b, AD[j], 0, 0, 0);
        AD[j] = __builtin_amdgcn_mfma_f32_16x16x32_bf16(ap1.b, bv1.b, AD[j], 0, 0, 0);
        AM[j] = __builtin_amdgcn_mfma_f32_16x16x32_bf16(as0.b, bm0.b, AM[j], 0, 0, 0);
        AM[j] = __builtin_amdgcn_mfma_f32_16x16x32_bf16(as1.b, bm1.b, AM[j], 0, 0, 0);
    }
    // ---- combine + store attn bf16
    #pragma unroll
    for (int j = 0; j < 4; ++j) {
        const int d = j * 16 + lm;
        const float zd = zr[d];
        #pragma unroll
        for (int r = 0; r < 4; ++r) {
            const int s_g = srow0 + r;
            const float den = rs[s_g] * zd + 1e-6f;
            const float o = gate * (AM[j][r] / den) + omg * AD[j][r];
            ab[base + (size_t)s_g * 64 + d] = f2bf(o);
        }
    }
}

extern "C" void kernel_launch(void* const* d_in, const int* in_sizes, int n_in,
                              void* d_out, int out_size, void* d_ws, size_t ws_size,
                              hipStream_t stream) {
    const float* x    = (const float*)d_in[0];
    const float* Wq   = (const float*)d_in[1];
    const float* bq   = (const float*)d_in[2];
    const float* Wk   = (const float*)d_in[3];
    const float* bk   = (const float*)d_in[4];
    const float* Wv   = (const float*)d_in[5];
    const float* bv   = (const float*)d_in[6];
    const float* Wo   = (const float*)d_in[7];
    const float* bo   = (const float*)d_in[8];
    const float* beta = (const float*)d_in[9];
    float* out = (float*)d_out;

    unsigned char* wsb = (unsigned char*)d_ws;
    unsigned short* xb  = (unsigned short*)(wsb);                       // 32 MB; reused as ab
    unsigned short* wb  = (unsigned short*)(wsb + (32ull << 20));       // 12 MB  [3072][2048]
    unsigned short* wob = (unsigned short*)(wsb + (44ull << 20));       // 2 MB   [1024][1024]
    unsigned short* qb  = (unsigned short*)(wsb + (46ull << 20));       // 16 MB
    unsigned short* kb  = (unsigned short*)(wsb + (62ull << 20));       // 16 MB
    unsigned short* vb  = (unsigned short*)(wsb + (78ull << 20));       // 16 MB
    float* Skv = (float*)(wsb + (94ull << 20));                         // 32 MB
    float* zc  = (float*)(wsb + (126ull << 20));                        // 0.5 MB
    unsigned short* ab = xb;   // attn bf16 (xb dead after gemm_qkv)

    cvt_all<<<11776, 256, 0, stream>>>(x, Wq, Wk, Wv, Wo, xb, wb, wob);

    gemm_qkv<<<dim3(24, 64), 256, 0, stream>>>(xb, wb, bq, bk, bv, qb, kb, vb);
    seg_kv<<<2048, 256, 0, stream>>>(kb, vb, Skv, zc);
    prefix_mem<<<dim3(8, 128), 256, 0, stream>>>(Skv, zc);
    seg_attn<<<2048, 256, 0, stream>>>(qb, kb, vb, Skv, zc, beta, ab);
    gemm_out<<<dim3(8, 64), 256, 0, stream>>>(ab, wob, bo, out);
}